// Round 11
// baseline (116.855 us; speedup 1.0000x reference)
//
#include <hip/hip_runtime.h>
#include <math.h>

#define BB 2
#define CC 256
#define GG 8
#define DD 32
#define HH 48
#define WW 48
#define HWSZ (HH*WW)        /* 2304 */
#define NHW (BB*HWSZ)       /* 4608 */
#define TOT (BB*CC*HWSZ)    /* 1179648 */
#define NBG (BB*GG)         /* 16 */
#define KSPLIT 4
#define KSEG (HWSZ/KSPLIT)  /* 576 keys per split = 9 tiles */
/* 1/sqrt(32) * log2(e): Q pre-scale so softmax runs in exp2 domain */
#define ATTN_SCALE (0.17677669529663687f * 1.4426950408889634f)

__device__ __align__(16) short g_q[NBG*HWSZ*DD];   // [bg][n][d] bf16, pre-scaled
__device__ __align__(16) short g_k[NBG*HWSZ*DD];   // [bg][n][d] bf16
__device__ __align__(16) short g_v[NBG*DD*HWSZ];   // [bg][d][n] bf16
__device__ __align__(16) float g_po[KSPLIT*NBG*DD*HWSZ]; // partial O (un-normalized)
__device__ __align__(16) float g_pl[KSPLIT*NBG*HWSZ];    // partial lsum
__device__ __align__(16) short g_wq[GG*9*2*16*32]; // [g][tap][mh][l15][ci] bf16
__device__ __align__(16) short g_wk[CC*DD];        // [c][ci] bf16
__device__ __align__(16) short g_wv[CC*DD];        // [c][ci] bf16

typedef __attribute__((ext_vector_type(8))) short bf16x8;
typedef __attribute__((ext_vector_type(4))) short s16x4;
typedef __attribute__((ext_vector_type(4))) float f32x4;

__device__ __forceinline__ short f2bf(float f) {
    union { float f; unsigned u; } uf; uf.f = f;
    unsigned r = uf.u + 0x7fff + ((uf.u >> 16) & 1);  // RNE
    return (short)(r >> 16);
}
__device__ __forceinline__ unsigned cvt_pk_bf16(float lo, float hi) {
    unsigned w;
    asm("v_cvt_pk_bf16_f32 %0, %1, %2" : "=v"(w) : "v"(lo), "v"(hi));
    return w;
}
#if __has_builtin(__builtin_amdgcn_exp2f)
#define EXP2F(x) __builtin_amdgcn_exp2f(x)
#else
#define EXP2F(x) exp2f(x)
#endif

// ---------------- weight pre-pack ----------------
__global__ __launch_bounds__(256) void pack_w(
    const float* __restrict__ Wq, const float* __restrict__ Wk,
    const float* __restrict__ Wv)
{
    int t = blockIdx.x * 256 + threadIdx.x;
    if (t < CC*DD*9) {                       // 73728
        int c = t / 288, r = t % 288, ci = r / 9, tap = r % 9;
        int g = c >> 5, mh = (c >> 4) & 1, l = c & 15;
        g_wq[(((g*9 + tap)*2 + mh)*16 + l)*32 + ci] = f2bf(Wq[t]);
    } else if (t < CC*DD*9 + CC*DD) {
        int i = t - CC*DD*9;
        g_wk[i] = f2bf(Wk[i]);
    } else if (t < CC*DD*9 + 2*CC*DD) {
        int i = t - CC*DD*9 - CC*DD;
        g_wv[i] = f2bf(Wv[i]);
    }
}

// ---------------- conv via implicit-GEMM MFMA ----------------
__global__ __launch_bounds__(256) void conv_mfma(
    const float* __restrict__ x,
    const float* __restrict__ bq, const float* __restrict__ bk,
    const float* __restrict__ bv)
{
    __shared__ __align__(16) short xt[8*48*40];   // [row][col][ci] pad 40

    int tid = threadIdx.x;
    int bg = blockIdx.x / 9;
    int pt = blockIdx.x % 9;
    int p0 = pt * 256;
    int b = bg >> 3, g = bg & 7;
    int r0 = p0 / 48 - 1;
    const float* xb = x + ((size_t)(b*CC + g*DD)) * HWSZ;

    for (int i = 0; i < 48; ++i) {
        int cell = tid + i * 256;
        int ci = cell / 384;
        int rc = cell % 384;
        int row = r0 + rc / 48, col = rc % 48;
        float v = (row >= 0 && row < 48) ? xb[(size_t)ci*HWSZ + row*48 + col] : 0.f;
        xt[rc*40 + ci] = f2bf(v);
    }
    __syncthreads();

    int lane = tid & 63, wave = tid >> 6;
    int l15 = lane & 15, lg = lane >> 4;

    bf16x8 aq[9][2], ak[2], av[2];
    const short* wqg = g_wq + g*9*2*16*32;
    #pragma unroll
    for (int tap = 0; tap < 9; ++tap)
        #pragma unroll
        for (int mh = 0; mh < 2; ++mh)
            aq[tap][mh] = *(const bf16x8*)&wqg[((tap*2 + mh)*16 + l15)*32 + lg*8];
    #pragma unroll
    for (int mh = 0; mh < 2; ++mh) {
        ak[mh] = *(const bf16x8*)&g_wk[(g*32 + mh*16 + l15)*32 + lg*8];
        av[mh] = *(const bf16x8*)&g_wv[(g*32 + mh*16 + l15)*32 + lg*8];
    }
    float bqv[2][4], bkv[2][4], bvv[2][4];
    #pragma unroll
    for (int mh = 0; mh < 2; ++mh)
        #pragma unroll
        for (int j = 0; j < 4; ++j) {
            int c = g*32 + mh*16 + lg*4 + j;
            bqv[mh][j] = bq[c]; bkv[mh][j] = bk[c]; bvv[mh][j] = bv[c];
        }

    int p0w = p0 + wave * 64;
    size_t qkb = (size_t)bg * HWSZ * DD;
    size_t vb  = (size_t)bg * DD * HWSZ;
    const f32x4 zero = {0.f,0.f,0.f,0.f};

    #pragma unroll
    for (int nf = 0; nf < 4; ++nf) {
        int n = p0w + nf*16 + l15;
        int y = n / 48, xcol = n % 48;
        int cell = (y - r0) * 48 + xcol;
        f32x4 cq0 = zero, cq1 = zero, ck0 = zero, ck1 = zero, cv0 = zero, cv1 = zero;
        #pragma unroll
        for (int tap = 0; tap < 9; ++tap) {
            int dy = tap / 3 - 1, dx = tap % 3 - 1;
            int xc = xcol + dx;
            bool ok = (unsigned)xc < 48u;
            int idx = ok ? (cell + dy*48 + dx)*40 + lg*8 : lg*8;
            bf16x8 bx = *(const bf16x8*)&xt[idx];
            if (!ok) bx = bf16x8{0,0,0,0,0,0,0,0};
            cq0 = __builtin_amdgcn_mfma_f32_16x16x32_bf16(aq[tap][0], bx, cq0, 0, 0, 0);
            cq1 = __builtin_amdgcn_mfma_f32_16x16x32_bf16(aq[tap][1], bx, cq1, 0, 0, 0);
            if (tap == 4) {
                ck0 = __builtin_amdgcn_mfma_f32_16x16x32_bf16(ak[0], bx, ck0, 0, 0, 0);
                ck1 = __builtin_amdgcn_mfma_f32_16x16x32_bf16(ak[1], bx, ck1, 0, 0, 0);
                cv0 = __builtin_amdgcn_mfma_f32_16x16x32_bf16(av[0], bx, cv0, 0, 0, 0);
                cv1 = __builtin_amdgcn_mfma_f32_16x16x32_bf16(av[1], bx, cv1, 0, 0, 0);
            }
        }
        #pragma unroll
        for (int mh = 0; mh < 2; ++mh) {
            f32x4 aQ = mh ? cq1 : cq0;
            f32x4 aK = mh ? ck1 : ck0;
            f32x4 aV = mh ? cv1 : cv0;
            s16x4 pq, pk;
            #pragma unroll
            for (int j = 0; j < 4; ++j) {
                pq[j] = f2bf((aQ[j] + bqv[mh][j]) * ATTN_SCALE);
                pk[j] = f2bf(aK[j] + bkv[mh][j]);
            }
            *(s16x4*)&g_q[qkb + (size_t)n*32 + mh*16 + lg*4] = pq;
            *(s16x4*)&g_k[qkb + (size_t)n*32 + mh*16 + lg*4] = pk;
            #pragma unroll
            for (int j = 0; j < 4; ++j)
                g_v[vb + (size_t)(mh*16 + lg*4 + j)*HWSZ + n] = f2bf(aV[j] + bvv[mh][j]);
        }
    }
}

// ---------------- attention: 32 q/wave, key-split partials ----------------
// grid 16bg x 72qt x 4ks = 4608 one-wave blocks; K/V loads amortized over 32 q.
__global__ __launch_bounds__(64, 4) void attn_mfma()
{
    __shared__ __align__(16) short p_lds[32][72];

    int lane = threadIdx.x;
    int l15 = lane & 15;
    int lg  = lane >> 4;
    int bg = blockIdx.x & 15;        // XCD clustering
    int r  = blockIdx.x >> 4;        // 0..287
    int ks = r & 3;
    int qt = r >> 2;                 // 0..71 (32-query tiles)
    int k0 = ks * KSEG;

    const short* qg = g_q + (size_t)bg * HWSZ * DD;
    const short* kg = g_k + (size_t)bg * HWSZ * DD;
    const short* vg = g_v + (size_t)bg * DD * HWSZ;

    bf16x8 aq0 = *(const bf16x8*)&qg[(size_t)(qt*32 + l15)*32 + lg*8];
    bf16x8 aq1 = *(const bf16x8*)&qg[(size_t)(qt*32 + 16 + l15)*32 + lg*8];

    f32x4 oc00 = {0.f,0.f,0.f,0.f}, oc01 = {0.f,0.f,0.f,0.f};
    f32x4 oc10 = {0.f,0.f,0.f,0.f}, oc11 = {0.f,0.f,0.f,0.f};
    const f32x4 zero = {0.f,0.f,0.f,0.f};
    float lsum0 = 0.f, lsum1 = 0.f;

    bf16x8 ck[4], cv[4];
    #pragma unroll
    for (int kb = 0; kb < 4; ++kb)
        ck[kb] = *(const bf16x8*)&kg[(size_t)(k0 + kb*16 + l15)*32 + lg*8];
    #pragma unroll
    for (int h = 0; h < 2; ++h)
        #pragma unroll
        for (int w = 0; w < 2; ++w)
            cv[h*2+w] = *(const bf16x8*)&vg[(size_t)(w*16 + l15)*HWSZ + k0 + h*32 + lg*8];

    #pragma unroll 3
    for (int t = 0; t < KSEG/64; ++t) {
        int mm = k0 + ((t + 1 < KSEG/64) ? (t + 1) * 64 : 0);
        bf16x8 nk[4], nv[4];
        #pragma unroll
        for (int kb = 0; kb < 4; ++kb)
            nk[kb] = *(const bf16x8*)&kg[(size_t)(mm + kb*16 + l15)*32 + lg*8];
        #pragma unroll
        for (int h = 0; h < 2; ++h)
            #pragma unroll
            for (int w = 0; w < 2; ++w)
                nv[h*2+w] = *(const bf16x8*)&vg[(size_t)(w*16 + l15)*HWSZ + mm + h*32 + lg*8];

        // q-frag 0: S^T rows 0..15
        {
            f32x4 s[4];
            #pragma unroll
            for (int kb = 0; kb < 4; ++kb)
                s[kb] = __builtin_amdgcn_mfma_f32_16x16x32_bf16(ck[kb], aq0, zero, 0, 0, 0);
            #pragma unroll
            for (int kb = 0; kb < 4; ++kb) {
                float p0 = EXP2F(s[kb][0]), p1 = EXP2F(s[kb][1]);
                float p2 = EXP2F(s[kb][2]), p3 = EXP2F(s[kb][3]);
                lsum0 += (p0 + p1) + (p2 + p3);
                uint2 w2;
                w2.x = cvt_pk_bf16(p0, p1);
                w2.y = cvt_pk_bf16(p2, p3);
                *(uint2*)&p_lds[l15][kb*16 + lg*4] = w2;
            }
        }
        // q-frag 1: S^T rows 16..31
        {
            f32x4 s[4];
            #pragma unroll
            for (int kb = 0; kb < 4; ++kb)
                s[kb] = __builtin_amdgcn_mfma_f32_16x16x32_bf16(ck[kb], aq1, zero, 0, 0, 0);
            #pragma unroll
            for (int kb = 0; kb < 4; ++kb) {
                float p0 = EXP2F(s[kb][0]), p1 = EXP2F(s[kb][1]);
                float p2 = EXP2F(s[kb][2]), p3 = EXP2F(s[kb][3]);
                lsum1 += (p0 + p1) + (p2 + p3);
                uint2 w2;
                w2.x = cvt_pk_bf16(p0, p1);
                w2.y = cvt_pk_bf16(p2, p3);
                *(uint2*)&p_lds[16 + l15][kb*16 + lg*4] = w2;
            }
        }

        // PV for both q-frags (wave-private LDS, no barrier)
        #pragma unroll
        for (int half = 0; half < 2; ++half) {
            bf16x8 pa0 = *(const bf16x8*)&p_lds[l15][half*32 + lg*8];
            bf16x8 pa1 = *(const bf16x8*)&p_lds[16 + l15][half*32 + lg*8];
            oc00 = __builtin_amdgcn_mfma_f32_16x16x32_bf16(cv[half*2+0], pa0, oc00, 0, 0, 0);
            oc01 = __builtin_amdgcn_mfma_f32_16x16x32_bf16(cv[half*2+1], pa0, oc01, 0, 0, 0);
            oc10 = __builtin_amdgcn_mfma_f32_16x16x32_bf16(cv[half*2+0], pa1, oc10, 0, 0, 0);
            oc11 = __builtin_amdgcn_mfma_f32_16x16x32_bf16(cv[half*2+1], pa1, oc11, 0, 0, 0);
        }

        #pragma unroll
        for (int kb = 0; kb < 4; ++kb) ck[kb] = nk[kb];
        #pragma unroll
        for (int i = 0; i < 4; ++i) cv[i] = nv[i];
    }

    // denominators (across lg groups; q = l15 column)
    lsum0 += __shfl_xor(lsum0, 16, 64);
    lsum0 += __shfl_xor(lsum0, 32, 64);
    lsum1 += __shfl_xor(lsum1, 16, 64);
    lsum1 += __shfl_xor(lsum1, 32, 64);

    int n0 = qt * 32 + l15;
    int n1 = n0 + 16;
    size_t pb = (size_t)(ks * NBG + bg) * DD * HWSZ;
    #pragma unroll
    for (int j = 0; j < 4; ++j) {
        g_po[pb + (size_t)(lg*4 + j) * HWSZ + n0]      = oc00[j];
        g_po[pb + (size_t)(16 + lg*4 + j) * HWSZ + n0] = oc01[j];
        g_po[pb + (size_t)(lg*4 + j) * HWSZ + n1]      = oc10[j];
        g_po[pb + (size_t)(16 + lg*4 + j) * HWSZ + n1] = oc11[j];
    }
    if (lg == 0) {
        g_pl[(size_t)(ks * NBG + bg) * HWSZ + n0] = lsum0;
        g_pl[(size_t)(ks * NBG + bg) * HWSZ + n1] = lsum1;
    }
}

// ---------------- combine partials + BN (batch stats) + affine + ReLU ----------------
__global__ __launch_bounds__(256) void bn_relu(
    const float* __restrict__ gamma, const float* __restrict__ beta,
    float* __restrict__ out)
{
    __shared__ float vbuf[2][HWSZ];           // combined attention output, 18.4 KB
    __shared__ float rs[4], rss[4];
    __shared__ float smean, sinv;
    int c = blockIdx.x;
    int tid = threadIdx.x;
    int g = c >> 5, d = c & 31;
    int bg0 = g, bg1 = 8 + g;                 // b=0,1

    float s = 0.f, ss = 0.f;
    for (int i = tid; i < HWSZ; i += 256) {
        float n0 = 0.f, d0 = 0.f, n1 = 0.f, d1 = 0.f;
        #pragma unroll
        for (int ks = 0; ks < KSPLIT; ++ks) {
            n0 += g_po[((size_t)(ks*NBG + bg0) * DD + d) * HWSZ + i];
            d0 += g_pl[(size_t)(ks*NBG + bg0) * HWSZ + i];
            n1 += g_po[((size_t)(ks*NBG + bg1) * DD + d) * HWSZ + i];
            d1 += g_pl[(size_t)(ks*NBG + bg1) * HWSZ + i];
        }
        float v0 = n0 / d0, v1 = n1 / d1;
        vbuf[0][i] = v0; vbuf[1][i] = v1;
        s += v0 + v1;
        ss += v0 * v0 + v1 * v1;
    }
    #pragma unroll
    for (int off = 32; off; off >>= 1) {
        s  += __shfl_down(s, off, 64);
        ss += __shfl_down(ss, off, 64);
    }
    int wid = tid >> 6, lane = tid & 63;
    if (lane == 0) { rs[wid] = s; rss[wid] = ss; }
    __syncthreads();
    if (tid == 0) {
        float ts  = rs[0] + rs[1] + rs[2] + rs[3];
        float tss = rss[0] + rss[1] + rss[2] + rss[3];
        float mean = ts / (float)NHW;
        float var  = tss / (float)NHW - mean * mean;
        smean = mean;
        sinv  = rsqrtf(var + 1e-5f);
    }
    __syncthreads();
    float mean = smean, inv = sinv;
    float ga = gamma[c], be = beta[c];
    float* out0 = out + (size_t)c * HWSZ;
    float* out1 = out + (size_t)(CC + c) * HWSZ;
    for (int i = tid; i < HWSZ; i += 256) {
        float v0 = (vbuf[0][i] - mean) * inv * ga + be;
        float v1 = (vbuf[1][i] - mean) * inv * ga + be;
        out0[i] = fmaxf(v0, 0.f);
        out1[i] = fmaxf(v1, 0.f);
    }
}

extern "C" void kernel_launch(void* const* d_in, const int* in_sizes, int n_in,
                              void* d_out, int out_size, void* d_ws, size_t ws_size,
                              hipStream_t stream)
{
    const float* x     = (const float*)d_in[0];
    const float* Wq    = (const float*)d_in[1];
    const float* bq    = (const float*)d_in[2];
    const float* Wk    = (const float*)d_in[3];
    const float* bk    = (const float*)d_in[4];
    const float* Wv    = (const float*)d_in[5];
    const float* bv    = (const float*)d_in[6];
    const float* gamma = (const float*)d_in[7];
    const float* beta  = (const float*)d_in[8];
    float* out = (float*)d_out;

    pack_w<<<(CC*DD*9 + 2*CC*DD + 255) / 256, 256, 0, stream>>>(Wq, Wk, Wv);
    conv_mfma<<<NBG * 9, 256, 0, stream>>>(x, bq, bk, bv);
    attn_mfma<<<NBG * 72 * KSPLIT, 64, 0, stream>>>();
    bn_relu<<<CC, 256, 0, stream>>>(gamma, beta, out);
}

// Round 12
// 101.041 us; speedup vs baseline: 1.1565x; 1.1565x over previous
//
#include <hip/hip_runtime.h>
#include <math.h>

#define BB 2
#define CC 256
#define GG 8
#define DD 32
#define HH 48
#define WW 48
#define HWSZ (HH*WW)        /* 2304 */
#define NHW (BB*HWSZ)       /* 4608 */
#define TOT (BB*CC*HWSZ)    /* 1179648 */
#define NBG (BB*GG)         /* 16 */
#define KSPLIT 4
#define KSEG (HWSZ/KSPLIT)  /* 576 keys per split = 9 tiles */
/* 1/sqrt(32) * log2(e): Q pre-scale so softmax runs in exp2 domain */
#define ATTN_SCALE (0.17677669529663687f * 1.4426950408889634f)

__device__ __align__(16) short g_q[NBG*HWSZ*DD];   // [bg][n][d] bf16, pre-scaled
__device__ __align__(16) short g_k[NBG*HWSZ*DD];   // [bg][n][d] bf16
__device__ __align__(16) short g_v[NBG*DD*HWSZ];   // [bg][d][n] bf16
__device__ __align__(16) float g_po[KSPLIT*NBG*DD*HWSZ]; // partial O (un-normalized)
__device__ __align__(16) float g_pl[KSPLIT*NBG*HWSZ];    // partial lsum
__device__ __align__(16) short g_wq[GG*9*2*16*32]; // [g][tap][mh][l15][ci] bf16
__device__ __align__(16) short g_wk[CC*DD];        // [c][ci] bf16
__device__ __align__(16) short g_wv[CC*DD];        // [c][ci] bf16

typedef __attribute__((ext_vector_type(8))) short bf16x8;
typedef __attribute__((ext_vector_type(4))) short s16x4;
typedef __attribute__((ext_vector_type(4))) float f32x4;

__device__ __forceinline__ short f2bf(float f) {
    union { float f; unsigned u; } uf; uf.f = f;
    unsigned r = uf.u + 0x7fff + ((uf.u >> 16) & 1);  // RNE
    return (short)(r >> 16);
}
__device__ __forceinline__ unsigned cvt_pk_bf16(float lo, float hi) {
    unsigned w;
    asm("v_cvt_pk_bf16_f32 %0, %1, %2" : "=v"(w) : "v"(lo), "v"(hi));
    return w;
}
#if __has_builtin(__builtin_amdgcn_exp2f)
#define EXP2F(x) __builtin_amdgcn_exp2f(x)
#else
#define EXP2F(x) exp2f(x)
#endif

// ---------------- weight pre-pack ----------------
__global__ __launch_bounds__(256) void pack_w(
    const float* __restrict__ Wq, const float* __restrict__ Wk,
    const float* __restrict__ Wv)
{
    int t = blockIdx.x * 256 + threadIdx.x;
    if (t < CC*DD*9) {                       // 73728
        int c = t / 288, r = t % 288, ci = r / 9, tap = r % 9;
        int g = c >> 5, mh = (c >> 4) & 1, l = c & 15;
        g_wq[(((g*9 + tap)*2 + mh)*16 + l)*32 + ci] = f2bf(Wq[t]);
    } else if (t < CC*DD*9 + CC*DD) {
        int i = t - CC*DD*9;
        g_wk[i] = f2bf(Wk[i]);
    } else if (t < CC*DD*9 + 2*CC*DD) {
        int i = t - CC*DD*9 - CC*DD;
        g_wv[i] = f2bf(Wv[i]);
    }
}

// ---------------- conv via implicit-GEMM MFMA ----------------
__global__ __launch_bounds__(256) void conv_mfma(
    const float* __restrict__ x,
    const float* __restrict__ bq, const float* __restrict__ bk,
    const float* __restrict__ bv)
{
    __shared__ __align__(16) short xt[8*48*40];   // [row][col][ci] pad 40

    int tid = threadIdx.x;
    int bg = blockIdx.x / 9;
    int pt = blockIdx.x % 9;
    int p0 = pt * 256;
    int b = bg >> 3, g = bg & 7;
    int r0 = p0 / 48 - 1;
    const float* xb = x + ((size_t)(b*CC + g*DD)) * HWSZ;

    for (int i = 0; i < 48; ++i) {
        int cell = tid + i * 256;
        int ci = cell / 384;
        int rc = cell % 384;
        int row = r0 + rc / 48, col = rc % 48;
        float v = (row >= 0 && row < 48) ? xb[(size_t)ci*HWSZ + row*48 + col] : 0.f;
        xt[rc*40 + ci] = f2bf(v);
    }
    __syncthreads();

    int lane = tid & 63, wave = tid >> 6;
    int l15 = lane & 15, lg = lane >> 4;

    bf16x8 aq[9][2], ak[2], av[2];
    const short* wqg = g_wq + g*9*2*16*32;
    #pragma unroll
    for (int tap = 0; tap < 9; ++tap)
        #pragma unroll
        for (int mh = 0; mh < 2; ++mh)
            aq[tap][mh] = *(const bf16x8*)&wqg[((tap*2 + mh)*16 + l15)*32 + lg*8];
    #pragma unroll
    for (int mh = 0; mh < 2; ++mh) {
        ak[mh] = *(const bf16x8*)&g_wk[(g*32 + mh*16 + l15)*32 + lg*8];
        av[mh] = *(const bf16x8*)&g_wv[(g*32 + mh*16 + l15)*32 + lg*8];
    }
    float bqv[2][4], bkv[2][4], bvv[2][4];
    #pragma unroll
    for (int mh = 0; mh < 2; ++mh)
        #pragma unroll
        for (int j = 0; j < 4; ++j) {
            int c = g*32 + mh*16 + lg*4 + j;
            bqv[mh][j] = bq[c]; bkv[mh][j] = bk[c]; bvv[mh][j] = bv[c];
        }

    int p0w = p0 + wave * 64;
    size_t qkb = (size_t)bg * HWSZ * DD;
    size_t vb  = (size_t)bg * DD * HWSZ;
    const f32x4 zero = {0.f,0.f,0.f,0.f};

    #pragma unroll
    for (int nf = 0; nf < 4; ++nf) {
        int n = p0w + nf*16 + l15;
        int y = n / 48, xcol = n % 48;
        int cell = (y - r0) * 48 + xcol;
        f32x4 cq0 = zero, cq1 = zero, ck0 = zero, ck1 = zero, cv0 = zero, cv1 = zero;
        #pragma unroll
        for (int tap = 0; tap < 9; ++tap) {
            int dy = tap / 3 - 1, dx = tap % 3 - 1;
            int xc = xcol + dx;
            bool ok = (unsigned)xc < 48u;
            int idx = ok ? (cell + dy*48 + dx)*40 + lg*8 : lg*8;
            bf16x8 bx = *(const bf16x8*)&xt[idx];
            if (!ok) bx = bf16x8{0,0,0,0,0,0,0,0};
            cq0 = __builtin_amdgcn_mfma_f32_16x16x32_bf16(aq[tap][0], bx, cq0, 0, 0, 0);
            cq1 = __builtin_amdgcn_mfma_f32_16x16x32_bf16(aq[tap][1], bx, cq1, 0, 0, 0);
            if (tap == 4) {
                ck0 = __builtin_amdgcn_mfma_f32_16x16x32_bf16(ak[0], bx, ck0, 0, 0, 0);
                ck1 = __builtin_amdgcn_mfma_f32_16x16x32_bf16(ak[1], bx, ck1, 0, 0, 0);
                cv0 = __builtin_amdgcn_mfma_f32_16x16x32_bf16(av[0], bx, cv0, 0, 0, 0);
                cv1 = __builtin_amdgcn_mfma_f32_16x16x32_bf16(av[1], bx, cv1, 0, 0, 0);
            }
        }
        #pragma unroll
        for (int mh = 0; mh < 2; ++mh) {
            f32x4 aQ = mh ? cq1 : cq0;
            f32x4 aK = mh ? ck1 : ck0;
            f32x4 aV = mh ? cv1 : cv0;
            s16x4 pq, pk;
            #pragma unroll
            for (int j = 0; j < 4; ++j) {
                pq[j] = f2bf((aQ[j] + bqv[mh][j]) * ATTN_SCALE);
                pk[j] = f2bf(aK[j] + bkv[mh][j]);
            }
            *(s16x4*)&g_q[qkb + (size_t)n*32 + mh*16 + lg*4] = pq;
            *(s16x4*)&g_k[qkb + (size_t)n*32 + mh*16 + lg*4] = pk;
            #pragma unroll
            for (int j = 0; j < 4; ++j)
                g_v[vb + (size_t)(mh*16 + lg*4 + j)*HWSZ + n] = f2bf(aV[j] + bvv[mh][j]);
        }
    }
}

// ---------------- attention: key-split, 4 waves/block, in-register P (permlane) ----------------
// block = 256 thr = 4 waves (= 4 ks segments), zero sync, zero LDS.
// P redistribution for PV done with permlane32/16_swap pairs (both outputs used).
__global__ __launch_bounds__(256) void attn_mfma()
{
    int tid  = threadIdx.x;
    int lane = tid & 63;
    int ks   = tid >> 6;             // wave = key-split segment
    int l15 = lane & 15;
    int lg  = lane >> 4;
    int bg = blockIdx.x & 15;        // XCD clustering: bg, bg+8 per XCD
    int qt = blockIdx.x >> 4;        // 0..143
    int k0 = ks * KSEG;

    const short* qg = g_q + (size_t)bg * HWSZ * DD;
    const short* kg = g_k + (size_t)bg * HWSZ * DD;
    const short* vg = g_v + (size_t)bg * DD * HWSZ;

    bf16x8 aq = *(const bf16x8*)&qg[(size_t)(qt*16 + l15)*32 + lg*8];

    f32x4 oc0 = {0.f,0.f,0.f,0.f}, oc1 = {0.f,0.f,0.f,0.f};
    const f32x4 zero = {0.f,0.f,0.f,0.f};
    float lsum = 0.f;

    bf16x8 ck[4], cv[4];
    #pragma unroll
    for (int kb = 0; kb < 4; ++kb)
        ck[kb] = *(const bf16x8*)&kg[(size_t)(k0 + kb*16 + l15)*32 + lg*8];
    #pragma unroll
    for (int h = 0; h < 2; ++h)
        #pragma unroll
        for (int w = 0; w < 2; ++w)
            cv[h*2+w] = *(const bf16x8*)&vg[(size_t)(w*16 + l15)*HWSZ + k0 + h*32 + lg*8];

    for (int t = 0; t < KSEG/64; ++t) {
        int mm = k0 + ((t + 1 < KSEG/64) ? (t + 1) * 64 : 0);
        bf16x8 nk[4], nv[4];
        #pragma unroll
        for (int kb = 0; kb < 4; ++kb)
            nk[kb] = *(const bf16x8*)&kg[(size_t)(mm + kb*16 + l15)*32 + lg*8];
        #pragma unroll
        for (int h = 0; h < 2; ++h)
            #pragma unroll
            for (int w = 0; w < 2; ++w)
                nv[h*2+w] = *(const bf16x8*)&vg[(size_t)(w*16 + l15)*HWSZ + mm + h*32 + lg*8];

        // S^T = K·Q^T : lane holds S[q=l15][k=kb*16+lg*4+j]
        f32x4 s[4];
        #pragma unroll
        for (int kb = 0; kb < 4; ++kb)
            s[kb] = __builtin_amdgcn_mfma_f32_16x16x32_bf16(ck[kb], aq, zero, 0, 0, 0);

        // p = exp2(s); pack pairs: W[kb][m] = bf16x2(p[kb*16+lg*4+2m], +1)
        unsigned W[4][2];
        #pragma unroll
        for (int kb = 0; kb < 4; ++kb) {
            float p0 = EXP2F(s[kb][0]), p1 = EXP2F(s[kb][1]);
            float p2 = EXP2F(s[kb][2]), p3 = EXP2F(s[kb][3]);
            lsum += (p0 + p1) + (p2 + p3);
            W[kb][0] = cvt_pk_bf16(p0, p1);
            W[kb][1] = cvt_pk_bf16(p2, p3);
        }

        // In-register P^T re-fragmentation:
        // (P,Q) = permlane32_swap(W[2h][m], W[2h+1][m]); (w_a, w_b) = permlane16_swap(P,Q)
        // gives frag rows [r0,r2] in w_a and [r1,r3] in w_b. Frag word order [a0,a1,b0,b1].
        #pragma unroll
        for (int h = 0; h < 2; ++h) {
            unsigned a0 = W[2*h][0], b0 = W[2*h+1][0];
            asm("v_permlane32_swap_b32 %0, %1" : "+v"(a0), "+v"(b0));
            asm("v_permlane16_swap_b32 %0, %1" : "+v"(a0), "+v"(b0));
            unsigned a1 = W[2*h][1], b1 = W[2*h+1][1];
            asm("v_permlane32_swap_b32 %0, %1" : "+v"(a1), "+v"(b1));
            asm("v_permlane16_swap_b32 %0, %1" : "+v"(a1), "+v"(b1));
            union { unsigned u[4]; bf16x8 v; } fr;
            fr.u[0] = a0; fr.u[1] = a1; fr.u[2] = b0; fr.u[3] = b1;
            oc0 = __builtin_amdgcn_mfma_f32_16x16x32_bf16(cv[h*2+0], fr.v, oc0, 0, 0, 0);
            oc1 = __builtin_amdgcn_mfma_f32_16x16x32_bf16(cv[h*2+1], fr.v, oc1, 0, 0, 0);
        }

        #pragma unroll
        for (int kb = 0; kb < 4; ++kb) ck[kb] = nk[kb];
        #pragma unroll
        for (int i = 0; i < 4; ++i) cv[i] = nv[i];
    }

    // denominator over this split (q = l15 column, across lg)
    lsum += __shfl_xor(lsum, 16, 64);
    lsum += __shfl_xor(lsum, 32, 64);

    int n = qt * 16 + l15;
    size_t pb = (size_t)(ks * NBG + bg) * DD * HWSZ;
    #pragma unroll
    for (int j = 0; j < 4; ++j) {
        g_po[pb + (size_t)(lg*4 + j) * HWSZ + n]      = oc0[j];
        g_po[pb + (size_t)(16 + lg*4 + j) * HWSZ + n] = oc1[j];
    }
    if (lg == 0) g_pl[(size_t)(ks * NBG + bg) * HWSZ + n] = lsum;
}

// ---------------- combine partials + BN (batch stats) + affine + ReLU ----------------
__global__ __launch_bounds__(256) void bn_relu(
    const float* __restrict__ gamma, const float* __restrict__ beta,
    float* __restrict__ out)
{
    __shared__ float vbuf[2][HWSZ];           // combined attention output, 18.4 KB
    __shared__ float rs[4], rss[4];
    __shared__ float smean, sinv;
    int c = blockIdx.x;
    int tid = threadIdx.x;
    int g = c >> 5, d = c & 31;
    int bg0 = g, bg1 = 8 + g;                 // b=0,1

    float s = 0.f, ss = 0.f;
    for (int i = tid; i < HWSZ; i += 256) {
        float n0 = 0.f, d0 = 0.f, n1 = 0.f, d1 = 0.f;
        #pragma unroll
        for (int ks = 0; ks < KSPLIT; ++ks) {
            n0 += g_po[((size_t)(ks*NBG + bg0) * DD + d) * HWSZ + i];
            d0 += g_pl[(size_t)(ks*NBG + bg0) * HWSZ + i];
            n1 += g_po[((size_t)(ks*NBG + bg1) * DD + d) * HWSZ + i];
            d1 += g_pl[(size_t)(ks*NBG + bg1) * HWSZ + i];
        }
        float v0 = n0 / d0, v1 = n1 / d1;
        vbuf[0][i] = v0; vbuf[1][i] = v1;
        s += v0 + v1;
        ss += v0 * v0 + v1 * v1;
    }
    #pragma unroll
    for (int off = 32; off; off >>= 1) {
        s  += __shfl_down(s, off, 64);
        ss += __shfl_down(ss, off, 64);
    }
    int wid = tid >> 6, lane = tid & 63;
    if (lane == 0) { rs[wid] = s; rss[wid] = ss; }
    __syncthreads();
    if (tid == 0) {
        float ts  = rs[0] + rs[1] + rs[2] + rs[3];
        float tss = rss[0] + rss[1] + rss[2] + rss[3];
        float mean = ts / (float)NHW;
        float var  = tss / (float)NHW - mean * mean;
        smean = mean;
        sinv  = rsqrtf(var + 1e-5f);
    }
    __syncthreads();
    float mean = smean, inv = sinv;
    float ga = gamma[c], be = beta[c];
    float* out0 = out + (size_t)c * HWSZ;
    float* out1 = out + (size_t)(CC + c) * HWSZ;
    for (int i = tid; i < HWSZ; i += 256) {
        float v0 = (vbuf[0][i] - mean) * inv * ga + be;
        float v1 = (vbuf[1][i] - mean) * inv * ga + be;
        out0[i] = fmaxf(v0, 0.f);
        out1[i] = fmaxf(v1, 0.f);
    }
}

extern "C" void kernel_launch(void* const* d_in, const int* in_sizes, int n_in,
                              void* d_out, int out_size, void* d_ws, size_t ws_size,
                              hipStream_t stream)
{
    const float* x     = (const float*)d_in[0];
    const float* Wq    = (const float*)d_in[1];
    const float* bq    = (const float*)d_in[2];
    const float* Wk    = (const float*)d_in[3];
    const float* bk    = (const float*)d_in[4];
    const float* Wv    = (const float*)d_in[5];
    const float* bv    = (const float*)d_in[6];
    const float* gamma = (const float*)d_in[7];
    const float* beta  = (const float*)d_in[8];
    float* out = (float*)d_out;

    pack_w<<<(CC*DD*9 + 2*CC*DD + 255) / 256, 256, 0, stream>>>(Wq, Wk, Wv);
    conv_mfma<<<NBG * 9, 256, 0, stream>>>(x, bq, bk, bv);
    attn_mfma<<<NBG * 144, 256, 0, stream>>>();
    bn_relu<<<CC, 256, 0, stream>>>(gamma, beta, out);
}

// Round 13
// 81.079 us; speedup vs baseline: 1.4412x; 1.2462x over previous
//
#include <hip/hip_runtime.h>
#include <math.h>

#define BB 2
#define CC 256
#define GG 8
#define DD 32
#define HH 48
#define WW 48
#define HWSZ (HH*WW)        /* 2304 */
#define NHW (BB*HWSZ)       /* 4608 */
#define TOT (BB*CC*HWSZ)    /* 1179648 */
#define NBG (BB*GG)         /* 16 */
#define KSPLIT 4
#define KSEG (HWSZ/KSPLIT)  /* 576 keys per split = 9 tiles */
#define VTILE 2048          /* shorts per V^T tile: 32 d x 64 keys */
/* 1/sqrt(32) * log2(e): Q pre-scale so softmax runs in exp2 domain */
#define ATTN_SCALE (0.17677669529663687f * 1.4426950408889634f)

__device__ __align__(16) short g_q[NBG*HWSZ*DD];   // [bg][n][d] bf16, pre-scaled
__device__ __align__(16) short g_k[NBG*HWSZ*DD];   // [bg][n][d] bf16
__device__ __align__(16) short g_v[NBG*DD*HWSZ];   // [bg][tile][d][64key] bf16 (V^T tiled)
__device__ __align__(16) float g_po[KSPLIT*NBG*DD*HWSZ]; // partial O (un-normalized)
__device__ __align__(16) float g_pl[KSPLIT*NBG*HWSZ];    // partial lsum
__device__ __align__(16) short g_wq[GG*9*2*16*32]; // [g][tap][mh][l15][ci] bf16
__device__ __align__(16) short g_wk[CC*DD];        // [c][ci] bf16
__device__ __align__(16) short g_wv[CC*DD];        // [c][ci] bf16

typedef __attribute__((ext_vector_type(8))) short bf16x8;
typedef __attribute__((ext_vector_type(4))) short s16x4;
typedef __attribute__((ext_vector_type(4))) float f32x4;

__device__ __forceinline__ short f2bf(float f) {
    union { float f; unsigned u; } uf; uf.f = f;
    unsigned r = uf.u + 0x7fff + ((uf.u >> 16) & 1);  // RNE
    return (short)(r >> 16);
}
__device__ __forceinline__ unsigned cvt_pk_bf16(float lo, float hi) {
    unsigned w;
    asm("v_cvt_pk_bf16_f32 %0, %1, %2" : "=v"(w) : "v"(lo), "v"(hi));
    return w;
}
#if __has_builtin(__builtin_amdgcn_exp2f)
#define EXP2F(x) __builtin_amdgcn_exp2f(x)
#else
#define EXP2F(x) exp2f(x)
#endif

// ---------------- weight pre-pack ----------------
__global__ __launch_bounds__(256) void pack_w(
    const float* __restrict__ Wq, const float* __restrict__ Wk,
    const float* __restrict__ Wv)
{
    int t = blockIdx.x * 256 + threadIdx.x;
    if (t < CC*DD*9) {                       // 73728
        int c = t / 288, r = t % 288, ci = r / 9, tap = r % 9;
        int g = c >> 5, mh = (c >> 4) & 1, l = c & 15;
        g_wq[(((g*9 + tap)*2 + mh)*16 + l)*32 + ci] = f2bf(Wq[t]);
    } else if (t < CC*DD*9 + CC*DD) {
        int i = t - CC*DD*9;
        g_wk[i] = f2bf(Wk[i]);
    } else if (t < CC*DD*9 + 2*CC*DD) {
        int i = t - CC*DD*9 - CC*DD;
        g_wv[i] = f2bf(Wv[i]);
    }
}

// ---------------- conv via implicit-GEMM MFMA ----------------
__global__ __launch_bounds__(256) void conv_mfma(
    const float* __restrict__ x,
    const float* __restrict__ bq, const float* __restrict__ bk,
    const float* __restrict__ bv)
{
    __shared__ __align__(16) short xt[8*48*40];   // [row][col][ci] pad 40

    int tid = threadIdx.x;
    int bg = blockIdx.x / 9;
    int pt = blockIdx.x % 9;
    int p0 = pt * 256;
    int b = bg >> 3, g = bg & 7;
    int r0 = p0 / 48 - 1;
    const float* xb = x + ((size_t)(b*CC + g*DD)) * HWSZ;

    for (int i = 0; i < 48; ++i) {
        int cell = tid + i * 256;
        int ci = cell / 384;
        int rc = cell % 384;
        int row = r0 + rc / 48, col = rc % 48;
        float v = (row >= 0 && row < 48) ? xb[(size_t)ci*HWSZ + row*48 + col] : 0.f;
        xt[rc*40 + ci] = f2bf(v);
    }
    __syncthreads();

    int lane = tid & 63, wave = tid >> 6;
    int l15 = lane & 15, lg = lane >> 4;

    bf16x8 aq[9][2], ak[2], av[2];
    const short* wqg = g_wq + g*9*2*16*32;
    #pragma unroll
    for (int tap = 0; tap < 9; ++tap)
        #pragma unroll
        for (int mh = 0; mh < 2; ++mh)
            aq[tap][mh] = *(const bf16x8*)&wqg[((tap*2 + mh)*16 + l15)*32 + lg*8];
    #pragma unroll
    for (int mh = 0; mh < 2; ++mh) {
        ak[mh] = *(const bf16x8*)&g_wk[(g*32 + mh*16 + l15)*32 + lg*8];
        av[mh] = *(const bf16x8*)&g_wv[(g*32 + mh*16 + l15)*32 + lg*8];
    }
    float bqv[2][4], bkv[2][4], bvv[2][4];
    #pragma unroll
    for (int mh = 0; mh < 2; ++mh)
        #pragma unroll
        for (int j = 0; j < 4; ++j) {
            int c = g*32 + mh*16 + lg*4 + j;
            bqv[mh][j] = bq[c]; bkv[mh][j] = bk[c]; bvv[mh][j] = bv[c];
        }

    int p0w = p0 + wave * 64;
    size_t qkb = (size_t)bg * HWSZ * DD;
    size_t vb  = (size_t)bg * DD * HWSZ;
    const f32x4 zero = {0.f,0.f,0.f,0.f};

    #pragma unroll
    for (int nf = 0; nf < 4; ++nf) {
        int n = p0w + nf*16 + l15;
        int y = n / 48, xcol = n % 48;
        int cell = (y - r0) * 48 + xcol;
        f32x4 cq0 = zero, cq1 = zero, ck0 = zero, ck1 = zero, cv0 = zero, cv1 = zero;
        #pragma unroll
        for (int tap = 0; tap < 9; ++tap) {
            int dy = tap / 3 - 1, dx = tap % 3 - 1;
            int xc = xcol + dx;
            bool ok = (unsigned)xc < 48u;
            int idx = ok ? (cell + dy*48 + dx)*40 + lg*8 : lg*8;
            bf16x8 bx = *(const bf16x8*)&xt[idx];
            if (!ok) bx = bf16x8{0,0,0,0,0,0,0,0};
            cq0 = __builtin_amdgcn_mfma_f32_16x16x32_bf16(aq[tap][0], bx, cq0, 0, 0, 0);
            cq1 = __builtin_amdgcn_mfma_f32_16x16x32_bf16(aq[tap][1], bx, cq1, 0, 0, 0);
            if (tap == 4) {
                ck0 = __builtin_amdgcn_mfma_f32_16x16x32_bf16(ak[0], bx, ck0, 0, 0, 0);
                ck1 = __builtin_amdgcn_mfma_f32_16x16x32_bf16(ak[1], bx, ck1, 0, 0, 0);
                cv0 = __builtin_amdgcn_mfma_f32_16x16x32_bf16(av[0], bx, cv0, 0, 0, 0);
                cv1 = __builtin_amdgcn_mfma_f32_16x16x32_bf16(av[1], bx, cv1, 0, 0, 0);
            }
        }
        int tile = n >> 6, key = n & 63;
        #pragma unroll
        for (int mh = 0; mh < 2; ++mh) {
            f32x4 aQ = mh ? cq1 : cq0;
            f32x4 aK = mh ? ck1 : ck0;
            f32x4 aV = mh ? cv1 : cv0;
            s16x4 pq, pk;
            #pragma unroll
            for (int j = 0; j < 4; ++j) {
                pq[j] = f2bf((aQ[j] + bqv[mh][j]) * ATTN_SCALE);
                pk[j] = f2bf(aK[j] + bkv[mh][j]);
            }
            *(s16x4*)&g_q[qkb + (size_t)n*32 + mh*16 + lg*4] = pq;
            *(s16x4*)&g_k[qkb + (size_t)n*32 + mh*16 + lg*4] = pk;
            #pragma unroll
            for (int j = 0; j < 4; ++j)
                g_v[vb + (size_t)tile*VTILE + (mh*16 + lg*4 + j)*64 + key]
                    = f2bf(aV[j] + bvv[mh][j]);
        }
    }
}

// ---------------- attention: 32q/wave, key-split, in-register P (permlane) ----------------
// block = 256 thr = 4 waves (= 4 ks segments), zero sync, zero LDS.
// Each wave: 32 queries (2 A-frags) x 576 keys; V^T tiled -> fully coalesced loads.
__global__ __launch_bounds__(256) void attn_mfma()
{
    int tid  = threadIdx.x;
    int lane = tid & 63;
    int ks   = tid >> 6;             // wave = key-split segment
    int l15 = lane & 15;
    int lg  = lane >> 4;
    int bg = blockIdx.x & 15;        // XCD clustering: bg, bg+8 per XCD
    int qt = blockIdx.x >> 4;        // 0..71 (32-query tiles)

    const short* qg = g_q + (size_t)bg * HWSZ * DD;
    const short* kg = g_k + (size_t)bg * HWSZ * DD;
    const short* vg = g_v + (size_t)bg * DD * HWSZ;
    int k0 = ks * KSEG;

    bf16x8 aq0 = *(const bf16x8*)&qg[(size_t)(qt*32 + l15)*32 + lg*8];
    bf16x8 aq1 = *(const bf16x8*)&qg[(size_t)(qt*32 + 16 + l15)*32 + lg*8];

    f32x4 oc00 = {0.f,0.f,0.f,0.f}, oc01 = {0.f,0.f,0.f,0.f};
    f32x4 oc10 = {0.f,0.f,0.f,0.f}, oc11 = {0.f,0.f,0.f,0.f};
    const f32x4 zero = {0.f,0.f,0.f,0.f};
    float lsum0 = 0.f, lsum1 = 0.f;

    bf16x8 ck[4], cv[4];
    #pragma unroll
    for (int kb = 0; kb < 4; ++kb)
        ck[kb] = *(const bf16x8*)&kg[(size_t)(k0 + kb*16 + l15)*32 + lg*8];
    {
        const short* vt = vg + (size_t)(ks*9) * VTILE;
        #pragma unroll
        for (int h = 0; h < 2; ++h)
            #pragma unroll
            for (int w = 0; w < 2; ++w)
                cv[h*2+w] = *(const bf16x8*)&vt[(w*16 + l15)*64 + h*32 + lg*8];
    }

    for (int t = 0; t < KSEG/64; ++t) {
        int tn = (t + 1 < KSEG/64) ? t + 1 : 0;
        int mm = k0 + tn * 64;
        const short* vtn = vg + (size_t)(ks*9 + tn) * VTILE;
        bf16x8 nk[4], nv[4];
        #pragma unroll
        for (int kb = 0; kb < 4; ++kb)
            nk[kb] = *(const bf16x8*)&kg[(size_t)(mm + kb*16 + l15)*32 + lg*8];
        #pragma unroll
        for (int h = 0; h < 2; ++h)
            #pragma unroll
            for (int w = 0; w < 2; ++w)
                nv[h*2+w] = *(const bf16x8*)&vtn[(w*16 + l15)*64 + h*32 + lg*8];

        // ---- q-frag 0 ----
        {
            f32x4 s[4];
            #pragma unroll
            for (int kb = 0; kb < 4; ++kb)
                s[kb] = __builtin_amdgcn_mfma_f32_16x16x32_bf16(ck[kb], aq0, zero, 0, 0, 0);
            unsigned W[4][2];
            #pragma unroll
            for (int kb = 0; kb < 4; ++kb) {
                float p0 = EXP2F(s[kb][0]), p1 = EXP2F(s[kb][1]);
                float p2 = EXP2F(s[kb][2]), p3 = EXP2F(s[kb][3]);
                lsum0 += (p0 + p1) + (p2 + p3);
                W[kb][0] = cvt_pk_bf16(p0, p1);
                W[kb][1] = cvt_pk_bf16(p2, p3);
            }
            #pragma unroll
            for (int h = 0; h < 2; ++h) {
                unsigned a0 = W[2*h][0], b0 = W[2*h+1][0];
                asm("v_permlane32_swap_b32 %0, %1" : "+v"(a0), "+v"(b0));
                asm("v_permlane16_swap_b32 %0, %1" : "+v"(a0), "+v"(b0));
                unsigned a1 = W[2*h][1], b1 = W[2*h+1][1];
                asm("v_permlane32_swap_b32 %0, %1" : "+v"(a1), "+v"(b1));
                asm("v_permlane16_swap_b32 %0, %1" : "+v"(a1), "+v"(b1));
                union { unsigned u[4]; bf16x8 v; } fr;
                fr.u[0] = a0; fr.u[1] = a1; fr.u[2] = b0; fr.u[3] = b1;
                oc00 = __builtin_amdgcn_mfma_f32_16x16x32_bf16(cv[h*2+0], fr.v, oc00, 0, 0, 0);
                oc01 = __builtin_amdgcn_mfma_f32_16x16x32_bf16(cv[h*2+1], fr.v, oc01, 0, 0, 0);
            }
        }
        // ---- q-frag 1 ----
        {
            f32x4 s[4];
            #pragma unroll
            for (int kb = 0; kb < 4; ++kb)
                s[kb] = __builtin_amdgcn_mfma_f32_16x16x32_bf16(ck[kb], aq1, zero, 0, 0, 0);
            unsigned W[4][2];
            #pragma unroll
            for (int kb = 0; kb < 4; ++kb) {
                float p0 = EXP2F(s[kb][0]), p1 = EXP2F(s[kb][1]);
                float p2 = EXP2F(s[kb][2]), p3 = EXP2F(s[kb][3]);
                lsum1 += (p0 + p1) + (p2 + p3);
                W[kb][0] = cvt_pk_bf16(p0, p1);
                W[kb][1] = cvt_pk_bf16(p2, p3);
            }
            #pragma unroll
            for (int h = 0; h < 2; ++h) {
                unsigned a0 = W[2*h][0], b0 = W[2*h+1][0];
                asm("v_permlane32_swap_b32 %0, %1" : "+v"(a0), "+v"(b0));
                asm("v_permlane16_swap_b32 %0, %1" : "+v"(a0), "+v"(b0));
                unsigned a1 = W[2*h][1], b1 = W[2*h+1][1];
                asm("v_permlane32_swap_b32 %0, %1" : "+v"(a1), "+v"(b1));
                asm("v_permlane16_swap_b32 %0, %1" : "+v"(a1), "+v"(b1));
                union { unsigned u[4]; bf16x8 v; } fr;
                fr.u[0] = a0; fr.u[1] = a1; fr.u[2] = b0; fr.u[3] = b1;
                oc10 = __builtin_amdgcn_mfma_f32_16x16x32_bf16(cv[h*2+0], fr.v, oc10, 0, 0, 0);
                oc11 = __builtin_amdgcn_mfma_f32_16x16x32_bf16(cv[h*2+1], fr.v, oc11, 0, 0, 0);
            }
        }

        #pragma unroll
        for (int kb = 0; kb < 4; ++kb) ck[kb] = nk[kb];
        #pragma unroll
        for (int i = 0; i < 4; ++i) cv[i] = nv[i];
    }

    // denominators (across lg groups; q = l15 column)
    lsum0 += __shfl_xor(lsum0, 16, 64);
    lsum0 += __shfl_xor(lsum0, 32, 64);
    lsum1 += __shfl_xor(lsum1, 16, 64);
    lsum1 += __shfl_xor(lsum1, 32, 64);

    int n0 = qt * 32 + l15;
    int n1 = n0 + 16;
    size_t pb = (size_t)(ks * NBG + bg) * DD * HWSZ;
    #pragma unroll
    for (int j = 0; j < 4; ++j) {
        g_po[pb + (size_t)(lg*4 + j) * HWSZ + n0]      = oc00[j];
        g_po[pb + (size_t)(16 + lg*4 + j) * HWSZ + n0] = oc01[j];
        g_po[pb + (size_t)(lg*4 + j) * HWSZ + n1]      = oc10[j];
        g_po[pb + (size_t)(16 + lg*4 + j) * HWSZ + n1] = oc11[j];
    }
    if (lg == 0) {
        g_pl[(size_t)(ks * NBG + bg) * HWSZ + n0] = lsum0;
        g_pl[(size_t)(ks * NBG + bg) * HWSZ + n1] = lsum1;
    }
}

// ---------------- combine partials + BN (batch stats) + affine + ReLU ----------------
__global__ __launch_bounds__(256) void bn_relu(
    const float* __restrict__ gamma, const float* __restrict__ beta,
    float* __restrict__ out)
{
    __shared__ float vbuf[2][HWSZ];           // combined attention output, 18.4 KB
    __shared__ float rs[4], rss[4];
    __shared__ float smean, sinv;
    int c = blockIdx.x;
    int tid = threadIdx.x;
    int g = c >> 5, d = c & 31;
    int bg0 = g, bg1 = 8 + g;                 // b=0,1

    float s = 0.f, ss = 0.f;
    for (int i = tid; i < HWSZ; i += 256) {
        float n0 = 0.f, d0 = 0.f, n1 = 0.f, d1 = 0.f;
        #pragma unroll
        for (int ks = 0; ks < KSPLIT; ++ks) {
            n0 += g_po[((size_t)(ks*NBG + bg0) * DD + d) * HWSZ + i];
            d0 += g_pl[(size_t)(ks*NBG + bg0) * HWSZ + i];
            n1 += g_po[((size_t)(ks*NBG + bg1) * DD + d) * HWSZ + i];
            d1 += g_pl[(size_t)(ks*NBG + bg1) * HWSZ + i];
        }
        float v0 = n0 / d0, v1 = n1 / d1;
        vbuf[0][i] = v0; vbuf[1][i] = v1;
        s += v0 + v1;
        ss += v0 * v0 + v1 * v1;
    }
    #pragma unroll
    for (int off = 32; off; off >>= 1) {
        s  += __shfl_down(s, off, 64);
        ss += __shfl_down(ss, off, 64);
    }
    int wid = tid >> 6, lane = tid & 63;
    if (lane == 0) { rs[wid] = s; rss[wid] = ss; }
    __syncthreads();
    if (tid == 0) {
        float ts  = rs[0] + rs[1] + rs[2] + rs[3];
        float tss = rss[0] + rss[1] + rss[2] + rss[3];
        float mean = ts / (float)NHW;
        float var  = tss / (float)NHW - mean * mean;
        smean = mean;
        sinv  = rsqrtf(var + 1e-5f);
    }
    __syncthreads();
    float mean = smean, inv = sinv;
    float ga = gamma[c], be = beta[c];
    float* out0 = out + (size_t)c * HWSZ;
    float* out1 = out + (size_t)(CC + c) * HWSZ;
    for (int i = tid; i < HWSZ; i += 256) {
        float v0 = (vbuf[0][i] - mean) * inv * ga + be;
        float v1 = (vbuf[1][i] - mean) * inv * ga + be;
        out0[i] = fmaxf(v0, 0.f);
        out1[i] = fmaxf(v1, 0.f);
    }
}

extern "C" void kernel_launch(void* const* d_in, const int* in_sizes, int n_in,
                              void* d_out, int out_size, void* d_ws, size_t ws_size,
                              hipStream_t stream)
{
    const float* x     = (const float*)d_in[0];
    const float* Wq    = (const float*)d_in[1];
    const float* bq    = (const float*)d_in[2];
    const float* Wk    = (const float*)d_in[3];
    const float* bk    = (const float*)d_in[4];
    const float* Wv    = (const float*)d_in[5];
    const float* bv    = (const float*)d_in[6];
    const float* gamma = (const float*)d_in[7];
    const float* beta  = (const float*)d_in[8];
    float* out = (float*)d_out;

    pack_w<<<(CC*DD*9 + 2*CC*DD + 255) / 256, 256, 0, stream>>>(Wq, Wk, Wv);
    conv_mfma<<<NBG * 9, 256, 0, stream>>>(x, bq, bk, bv);
    attn_mfma<<<NBG * 72, 256, 0, stream>>>();
    bn_relu<<<CC, 256, 0, stream>>>(gamma, beta, out);
}

// Round 14
// 65.345 us; speedup vs baseline: 1.7883x; 1.2408x over previous
//
#include <hip/hip_runtime.h>
#include <math.h>

#define BB 2
#define CC 256
#define GG 8
#define DD 32
#define HH 48
#define WW 48
#define HWSZ (HH*WW)        /* 2304 */
#define NHW (BB*HWSZ)       /* 4608 */
#define TOT (BB*CC*HWSZ)    /* 1179648 */
#define NBG (BB*GG)         /* 16 */
#define KSPLIT 4
#define KSEG (HWSZ/KSPLIT)  /* 576 keys per split = 9 tiles */
#define VTILE 2048          /* shorts per V^T tile: 32 d x 64 keys */
/* 1/sqrt(32) * log2(e): Q pre-scale so softmax runs in exp2 domain */
#define ATTN_SCALE (0.17677669529663687f * 1.4426950408889634f)

__device__ __align__(16) short g_q[NBG*HWSZ*DD];   // [bg][n][d] bf16, pre-scaled
__device__ __align__(16) short g_k[NBG*HWSZ*DD];   // [bg][n][d] bf16
__device__ __align__(16) short g_v[NBG*DD*HWSZ];   // [bg][tile][d][64key] bf16 (V^T tiled)
__device__ __align__(16) float g_po[KSPLIT*NBG*DD*HWSZ]; // partial O (un-normalized)
__device__ __align__(16) float g_pl[KSPLIT*NBG*HWSZ];    // partial lsum
__device__ __align__(16) short g_wq[GG*9*2*16*32]; // [g][tap][mh][l15][ci] bf16
__device__ __align__(16) short g_wk[CC*DD];        // [c][ci] bf16
__device__ __align__(16) short g_wv[CC*DD];        // [c][ci] bf16

typedef __attribute__((ext_vector_type(8))) short bf16x8;
typedef __attribute__((ext_vector_type(4))) short s16x4;
typedef __attribute__((ext_vector_type(4))) float f32x4;

__device__ __forceinline__ short f2bf(float f) {
    union { float f; unsigned u; } uf; uf.f = f;
    unsigned r = uf.u + 0x7fff + ((uf.u >> 16) & 1);  // RNE
    return (short)(r >> 16);
}
__device__ __forceinline__ unsigned cvt_pk_bf16(float lo, float hi) {
    unsigned w;
    asm("v_cvt_pk_bf16_f32 %0, %1, %2" : "=v"(w) : "v"(lo), "v"(hi));
    return w;
}
#if __has_builtin(__builtin_amdgcn_exp2f)
#define EXP2F(x) __builtin_amdgcn_exp2f(x)
#else
#define EXP2F(x) exp2f(x)
#endif

// ---------------- weight pre-pack ----------------
__global__ __launch_bounds__(256) void pack_w(
    const float* __restrict__ Wq, const float* __restrict__ Wk,
    const float* __restrict__ Wv)
{
    int t = blockIdx.x * 256 + threadIdx.x;
    if (t < CC*DD*9) {                       // 73728
        int c = t / 288, r = t % 288, ci = r / 9, tap = r % 9;
        int g = c >> 5, mh = (c >> 4) & 1, l = c & 15;
        g_wq[(((g*9 + tap)*2 + mh)*16 + l)*32 + ci] = f2bf(Wq[t]);
    } else if (t < CC*DD*9 + CC*DD) {
        int i = t - CC*DD*9;
        g_wk[i] = f2bf(Wk[i]);
    } else if (t < CC*DD*9 + 2*CC*DD) {
        int i = t - CC*DD*9 - CC*DD;
        g_wv[i] = f2bf(Wv[i]);
    }
}

// ---------------- conv via implicit-GEMM MFMA: 288 blocks x 128 positions ----------------
__global__ __launch_bounds__(256) void conv_mfma(
    const float* __restrict__ x,
    const float* __restrict__ bq, const float* __restrict__ bk,
    const float* __restrict__ bv)
{
    __shared__ __align__(16) short xt[6*48*32];   // 6-row window [rc][ci], 18 KB

    int tid = threadIdx.x;
    int bg = blockIdx.x / 18;
    int pt = blockIdx.x % 18;
    int p0 = pt * 128;
    int b = bg >> 3, g = bg & 7;
    int r0 = p0 / 48 - 1;                    // 6 staged rows r0..r0+5
    const float* xb = x + ((size_t)(b*CC + g*DD)) * HWSZ;

    #pragma unroll 6
    for (int i = 0; i < 36; ++i) {
        int cell = tid + i * 256;            // 9216 = 32ci * 288rc
        int ci = cell / 288;
        int rc = cell % 288;
        int row = r0 + rc / 48, col = rc % 48;
        float v = (row >= 0 && row < 48) ? xb[(size_t)ci*HWSZ + row*48 + col] : 0.f;
        xt[rc*32 + ci] = f2bf(v);
    }
    __syncthreads();

    int lane = tid & 63, wave = tid >> 6;
    int l15 = lane & 15, lg = lane >> 4;

    bf16x8 aq[9][2], ak[2], av[2];
    const short* wqg = g_wq + g*9*2*16*32;
    #pragma unroll
    for (int tap = 0; tap < 9; ++tap)
        #pragma unroll
        for (int mh = 0; mh < 2; ++mh)
            aq[tap][mh] = *(const bf16x8*)&wqg[((tap*2 + mh)*16 + l15)*32 + lg*8];
    #pragma unroll
    for (int mh = 0; mh < 2; ++mh) {
        ak[mh] = *(const bf16x8*)&g_wk[(g*32 + mh*16 + l15)*32 + lg*8];
        av[mh] = *(const bf16x8*)&g_wv[(g*32 + mh*16 + l15)*32 + lg*8];
    }
    float bqv[2][4], bkv[2][4], bvv[2][4];
    #pragma unroll
    for (int mh = 0; mh < 2; ++mh)
        #pragma unroll
        for (int j = 0; j < 4; ++j) {
            int c = g*32 + mh*16 + lg*4 + j;
            bqv[mh][j] = bq[c]; bkv[mh][j] = bk[c]; bvv[mh][j] = bv[c];
        }

    int p0w = p0 + wave * 32;
    size_t qkb = (size_t)bg * HWSZ * DD;
    size_t vb  = (size_t)bg * DD * HWSZ;
    const f32x4 zero = {0.f,0.f,0.f,0.f};

    #pragma unroll
    for (int nf = 0; nf < 2; ++nf) {
        int n = p0w + nf*16 + l15;
        int y = n / 48, xcol = n % 48;
        int cell = (y - r0) * 48 + xcol;
        f32x4 cq0 = zero, cq1 = zero, ck0 = zero, ck1 = zero, cv0 = zero, cv1 = zero;
        #pragma unroll
        for (int tap = 0; tap < 9; ++tap) {
            int dy = tap / 3 - 1, dx = tap % 3 - 1;
            int xc = xcol + dx;
            bool ok = (unsigned)xc < 48u;
            int idx = ok ? (cell + dy*48 + dx)*32 + lg*8 : lg*8;
            bf16x8 bx = *(const bf16x8*)&xt[idx];
            if (!ok) bx = bf16x8{0,0,0,0,0,0,0,0};
            cq0 = __builtin_amdgcn_mfma_f32_16x16x32_bf16(aq[tap][0], bx, cq0, 0, 0, 0);
            cq1 = __builtin_amdgcn_mfma_f32_16x16x32_bf16(aq[tap][1], bx, cq1, 0, 0, 0);
            if (tap == 4) {
                ck0 = __builtin_amdgcn_mfma_f32_16x16x32_bf16(ak[0], bx, ck0, 0, 0, 0);
                ck1 = __builtin_amdgcn_mfma_f32_16x16x32_bf16(ak[1], bx, ck1, 0, 0, 0);
                cv0 = __builtin_amdgcn_mfma_f32_16x16x32_bf16(av[0], bx, cv0, 0, 0, 0);
                cv1 = __builtin_amdgcn_mfma_f32_16x16x32_bf16(av[1], bx, cv1, 0, 0, 0);
            }
        }
        int tile = n >> 6, key = n & 63;
        #pragma unroll
        for (int mh = 0; mh < 2; ++mh) {
            f32x4 aQ = mh ? cq1 : cq0;
            f32x4 aK = mh ? ck1 : ck0;
            f32x4 aV = mh ? cv1 : cv0;
            s16x4 pq, pk;
            #pragma unroll
            for (int j = 0; j < 4; ++j) {
                pq[j] = f2bf((aQ[j] + bqv[mh][j]) * ATTN_SCALE);
                pk[j] = f2bf(aK[j] + bkv[mh][j]);
            }
            *(s16x4*)&g_q[qkb + (size_t)n*32 + mh*16 + lg*4] = pq;
            *(s16x4*)&g_k[qkb + (size_t)n*32 + mh*16 + lg*4] = pk;
            #pragma unroll
            for (int j = 0; j < 4; ++j)
                g_v[vb + (size_t)tile*VTILE + (mh*16 + lg*4 + j)*64 + key]
                    = f2bf(aV[j] + bvv[mh][j]);
        }
    }
}

// ---------------- attention: 48q/wave, key-split, in-register P (permlane) ----------------
// block = 256 thr = 4 waves (= 4 ks segments), zero sync, zero LDS.
// Each wave: 48 queries (3 A-frags) x 576 keys; grid 768 = exactly 3 blocks/CU.
__global__ __launch_bounds__(256) void attn_mfma()
{
    int tid  = threadIdx.x;
    int lane = tid & 63;
    int ks   = tid >> 6;             // wave = key-split segment
    int l15 = lane & 15;
    int lg  = lane >> 4;
    int bg = blockIdx.x & 15;        // XCD clustering: bg, bg+8 per XCD
    int qt = blockIdx.x >> 4;        // 0..47 (48-query tiles)

    const short* qg = g_q + (size_t)bg * HWSZ * DD;
    const short* kg = g_k + (size_t)bg * HWSZ * DD;
    const short* vg = g_v + (size_t)bg * DD * HWSZ;
    int k0 = ks * KSEG;

    bf16x8 aq0 = *(const bf16x8*)&qg[(size_t)(qt*48 + l15)*32 + lg*8];
    bf16x8 aq1 = *(const bf16x8*)&qg[(size_t)(qt*48 + 16 + l15)*32 + lg*8];
    bf16x8 aq2 = *(const bf16x8*)&qg[(size_t)(qt*48 + 32 + l15)*32 + lg*8];

    f32x4 oc00 = {0.f,0.f,0.f,0.f}, oc01 = {0.f,0.f,0.f,0.f};
    f32x4 oc10 = {0.f,0.f,0.f,0.f}, oc11 = {0.f,0.f,0.f,0.f};
    f32x4 oc20 = {0.f,0.f,0.f,0.f}, oc21 = {0.f,0.f,0.f,0.f};
    const f32x4 zero = {0.f,0.f,0.f,0.f};
    float lsum0 = 0.f, lsum1 = 0.f, lsum2 = 0.f;

    bf16x8 ck[4], cv[4];
    #pragma unroll
    for (int kb = 0; kb < 4; ++kb)
        ck[kb] = *(const bf16x8*)&kg[(size_t)(k0 + kb*16 + l15)*32 + lg*8];
    {
        const short* vt = vg + (size_t)(ks*9) * VTILE;
        #pragma unroll
        for (int h = 0; h < 2; ++h)
            #pragma unroll
            for (int w = 0; w < 2; ++w)
                cv[h*2+w] = *(const bf16x8*)&vt[(w*16 + l15)*64 + h*32 + lg*8];
    }

    for (int t = 0; t < KSEG/64; ++t) {
        int tn = (t + 1 < KSEG/64) ? t + 1 : 0;
        int mm = k0 + tn * 64;
        const short* vtn = vg + (size_t)(ks*9 + tn) * VTILE;
        bf16x8 nk[4], nv[4];
        #pragma unroll
        for (int kb = 0; kb < 4; ++kb)
            nk[kb] = *(const bf16x8*)&kg[(size_t)(mm + kb*16 + l15)*32 + lg*8];
        #pragma unroll
        for (int h = 0; h < 2; ++h)
            #pragma unroll
            for (int w = 0; w < 2; ++w)
                nv[h*2+w] = *(const bf16x8*)&vtn[(w*16 + l15)*64 + h*32 + lg*8];

        #pragma unroll
        for (int qf = 0; qf < 3; ++qf) {
            bf16x8 aq = qf == 0 ? aq0 : (qf == 1 ? aq1 : aq2);
            f32x4 s[4];
            #pragma unroll
            for (int kb = 0; kb < 4; ++kb)
                s[kb] = __builtin_amdgcn_mfma_f32_16x16x32_bf16(ck[kb], aq, zero, 0, 0, 0);
            unsigned W[4][2];
            float ls = 0.f;
            #pragma unroll
            for (int kb = 0; kb < 4; ++kb) {
                float p0 = EXP2F(s[kb][0]), p1 = EXP2F(s[kb][1]);
                float p2 = EXP2F(s[kb][2]), p3 = EXP2F(s[kb][3]);
                ls += (p0 + p1) + (p2 + p3);
                W[kb][0] = cvt_pk_bf16(p0, p1);
                W[kb][1] = cvt_pk_bf16(p2, p3);
            }
            if (qf == 0) lsum0 += ls; else if (qf == 1) lsum1 += ls; else lsum2 += ls;
            #pragma unroll
            for (int h = 0; h < 2; ++h) {
                unsigned a0 = W[2*h][0], b0 = W[2*h+1][0];
                asm("v_permlane32_swap_b32 %0, %1" : "+v"(a0), "+v"(b0));
                asm("v_permlane16_swap_b32 %0, %1" : "+v"(a0), "+v"(b0));
                unsigned a1 = W[2*h][1], b1 = W[2*h+1][1];
                asm("v_permlane32_swap_b32 %0, %1" : "+v"(a1), "+v"(b1));
                asm("v_permlane16_swap_b32 %0, %1" : "+v"(a1), "+v"(b1));
                union { unsigned u[4]; bf16x8 v; } fr;
                fr.u[0] = a0; fr.u[1] = a1; fr.u[2] = b0; fr.u[3] = b1;
                if (qf == 0) {
                    oc00 = __builtin_amdgcn_mfma_f32_16x16x32_bf16(cv[h*2+0], fr.v, oc00, 0, 0, 0);
                    oc01 = __builtin_amdgcn_mfma_f32_16x16x32_bf16(cv[h*2+1], fr.v, oc01, 0, 0, 0);
                } else if (qf == 1) {
                    oc10 = __builtin_amdgcn_mfma_f32_16x16x32_bf16(cv[h*2+0], fr.v, oc10, 0, 0, 0);
                    oc11 = __builtin_amdgcn_mfma_f32_16x16x32_bf16(cv[h*2+1], fr.v, oc11, 0, 0, 0);
                } else {
                    oc20 = __builtin_amdgcn_mfma_f32_16x16x32_bf16(cv[h*2+0], fr.v, oc20, 0, 0, 0);
                    oc21 = __builtin_amdgcn_mfma_f32_16x16x32_bf16(cv[h*2+1], fr.v, oc21, 0, 0, 0);
                }
            }
        }

        #pragma unroll
        for (int kb = 0; kb < 4; ++kb) ck[kb] = nk[kb];
        #pragma unroll
        for (int i = 0; i < 4; ++i) cv[i] = nv[i];
    }

    // denominators (across lg groups; q = l15 column)
    lsum0 += __shfl_xor(lsum0, 16, 64);
    lsum0 += __shfl_xor(lsum0, 32, 64);
    lsum1 += __shfl_xor(lsum1, 16, 64);
    lsum1 += __shfl_xor(lsum1, 32, 64);
    lsum2 += __shfl_xor(lsum2, 16, 64);
    lsum2 += __shfl_xor(lsum2, 32, 64);

    int n0 = qt * 48 + l15;
    size_t pb = (size_t)(ks * NBG + bg) * DD * HWSZ;
    #pragma unroll
    for (int j = 0; j < 4; ++j) {
        g_po[pb + (size_t)(lg*4 + j) * HWSZ + n0]           = oc00[j];
        g_po[pb + (size_t)(16 + lg*4 + j) * HWSZ + n0]      = oc01[j];
        g_po[pb + (size_t)(lg*4 + j) * HWSZ + n0 + 16]      = oc10[j];
        g_po[pb + (size_t)(16 + lg*4 + j) * HWSZ + n0 + 16] = oc11[j];
        g_po[pb + (size_t)(lg*4 + j) * HWSZ + n0 + 32]      = oc20[j];
        g_po[pb + (size_t)(16 + lg*4 + j) * HWSZ + n0 + 32] = oc21[j];
    }
    if (lg == 0) {
        g_pl[(size_t)(ks * NBG + bg) * HWSZ + n0]      = lsum0;
        g_pl[(size_t)(ks * NBG + bg) * HWSZ + n0 + 16] = lsum1;
        g_pl[(size_t)(ks * NBG + bg) * HWSZ + n0 + 32] = lsum2;
    }
}

// ---------------- combine partials + BN (batch stats) + affine + ReLU ----------------
__global__ __launch_bounds__(256) void bn_relu(
    const float* __restrict__ gamma, const float* __restrict__ beta,
    float* __restrict__ out)
{
    __shared__ float vbuf[2][HWSZ];           // combined attention output, 18.4 KB
    __shared__ float rs[4], rss[4];
    __shared__ float smean, sinv;
    int c = blockIdx.x;
    int tid = threadIdx.x;
    int g = c >> 5, d = c & 31;
    int bg0 = g, bg1 = 8 + g;                 // b=0,1

    float s = 0.f, ss = 0.f;
    for (int i = tid; i < HWSZ; i += 256) {
        float n0 = 0.f, d0 = 0.f, n1 = 0.f, d1 = 0.f;
        #pragma unroll
        for (int ks = 0; ks < KSPLIT; ++ks) {
            n0 += g_po[((size_t)(ks*NBG + bg0) * DD + d) * HWSZ + i];
            d0 += g_pl[(size_t)(ks*NBG + bg0) * HWSZ + i];
            n1 += g_po[((size_t)(ks*NBG + bg1) * DD + d) * HWSZ + i];
            d1 += g_pl[(size_t)(ks*NBG + bg1) * HWSZ + i];
        }
        float v0 = n0 / d0, v1 = n1 / d1;
        vbuf[0][i] = v0; vbuf[1][i] = v1;
        s += v0 + v1;
        ss += v0 * v0 + v1 * v1;
    }
    #pragma unroll
    for (int off = 32; off; off >>= 1) {
        s  += __shfl_down(s, off, 64);
        ss += __shfl_down(ss, off, 64);
    }
    int wid = tid >> 6, lane = tid & 63;
    if (lane == 0) { rs[wid] = s; rss[wid] = ss; }
    __syncthreads();
    if (tid == 0) {
        float ts  = rs[0] + rs[1] + rs[2] + rs[3];
        float tss = rss[0] + rss[1] + rss[2] + rss[3];
        float mean = ts / (float)NHW;
        float var  = tss / (float)NHW - mean * mean;
        smean = mean;
        sinv  = rsqrtf(var + 1e-5f);
    }
    __syncthreads();
    float mean = smean, inv = sinv;
    float ga = gamma[c], be = beta[c];
    float* out0 = out + (size_t)c * HWSZ;
    float* out1 = out + (size_t)(CC + c) * HWSZ;
    for (int i = tid; i < HWSZ; i += 256) {
        float v0 = (vbuf[0][i] - mean) * inv * ga + be;
        float v1 = (vbuf[1][i] - mean) * inv * ga + be;
        out0[i] = fmaxf(v0, 0.f);
        out1[i] = fmaxf(v1, 0.f);
    }
}

extern "C" void kernel_launch(void* const* d_in, const int* in_sizes, int n_in,
                              void* d_out, int out_size, void* d_ws, size_t ws_size,
                              hipStream_t stream)
{
    const float* x     = (const float*)d_in[0];
    const float* Wq    = (const float*)d_in[1];
    const float* bq    = (const float*)d_in[2];
    const float* Wk    = (const float*)d_in[3];
    const float* bk    = (const float*)d_in[4];
    const float* Wv    = (const float*)d_in[5];
    const float* bv    = (const float*)d_in[6];
    const float* gamma = (const float*)d_in[7];
    const float* beta  = (const float*)d_in[8];
    float* out = (float*)d_out;

    pack_w<<<(CC*DD*9 + 2*CC*DD + 255) / 256, 256, 0, stream>>>(Wq, Wk, Wv);
    conv_mfma<<<NBG * 18, 256, 0, stream>>>(x, bq, bk, bv);
    attn_mfma<<<NBG * 48, 256, 0, stream>>>();
    bn_relu<<<CC, 256, 0, stream>>>(gamma, beta, out);
}

// Round 15
// 58.193 us; speedup vs baseline: 2.0081x; 1.1229x over previous
//
#include <hip/hip_runtime.h>
#include <math.h>

#define BB 2
#define CC 256
#define GG 8
#define DD 32
#define HH 48
#define WW 48
#define HWSZ (HH*WW)        /* 2304 */
#define NHW (BB*HWSZ)       /* 4608 */
#define TOT (BB*CC*HWSZ)    /* 1179648 */
#define NBG (BB*GG)         /* 16 */
#define KSPLIT 4
#define KSEG (HWSZ/KSPLIT)  /* 576 keys per split = 9 tiles */
#define VTILE 2048          /* shorts per V^T tile: 32 d x 64 keys */
/* 1/sqrt(32) * log2(e): Q pre-scale so softmax runs in exp2 domain */
#define ATTN_SCALE (0.17677669529663687f * 1.4426950408889634f)

__device__ __align__(16) short g_q[NBG*HWSZ*DD];   // [bg][n][d] bf16, pre-scaled
__device__ __align__(16) short g_k[NBG*HWSZ*DD];   // [bg][n][d] bf16
__device__ __align__(16) short g_v[NBG*DD*HWSZ];   // [bg][tile][d][64key] bf16 (V^T tiled)
__device__ __align__(16) float g_o[TOT];           // [bg][d][n] fp32 (= channel-major)
__device__ __align__(16) short g_wq[GG*9*2*16*32]; // [g][tap][mh][l15][ci] bf16
__device__ __align__(16) short g_wk[CC*DD];        // [c][ci] bf16
__device__ __align__(16) short g_wv[CC*DD];        // [c][ci] bf16

typedef __attribute__((ext_vector_type(8))) short bf16x8;
typedef __attribute__((ext_vector_type(4))) short s16x4;
typedef __attribute__((ext_vector_type(4))) float f32x4;

__device__ __forceinline__ short f2bf(float f) {
    union { float f; unsigned u; } uf; uf.f = f;
    unsigned r = uf.u + 0x7fff + ((uf.u >> 16) & 1);  // RNE
    return (short)(r >> 16);
}
__device__ __forceinline__ unsigned cvt_pk_bf16(float lo, float hi) {
    unsigned w;
    asm("v_cvt_pk_bf16_f32 %0, %1, %2" : "=v"(w) : "v"(lo), "v"(hi));
    return w;
}
#if __has_builtin(__builtin_amdgcn_exp2f)
#define EXP2F(x) __builtin_amdgcn_exp2f(x)
#else
#define EXP2F(x) exp2f(x)
#endif

// ---------------- weight pre-pack ----------------
__global__ __launch_bounds__(256) void pack_w(
    const float* __restrict__ Wq, const float* __restrict__ Wk,
    const float* __restrict__ Wv)
{
    int t = blockIdx.x * 256 + threadIdx.x;
    if (t < CC*DD*9) {                       // 73728
        int c = t / 288, r = t % 288, ci = r / 9, tap = r % 9;
        int g = c >> 5, mh = (c >> 4) & 1, l = c & 15;
        g_wq[(((g*9 + tap)*2 + mh)*16 + l)*32 + ci] = f2bf(Wq[t]);
    } else if (t < CC*DD*9 + CC*DD) {
        int i = t - CC*DD*9;
        g_wk[i] = f2bf(Wk[i]);
    } else if (t < CC*DD*9 + 2*CC*DD) {
        int i = t - CC*DD*9 - CC*DD;
        g_wv[i] = f2bf(Wv[i]);
    }
}

// ---------------- conv via implicit-GEMM MFMA: 288 blocks x 128 positions ----------------
__global__ __launch_bounds__(256) void conv_mfma(
    const float* __restrict__ x,
    const float* __restrict__ bq, const float* __restrict__ bk,
    const float* __restrict__ bv)
{
    __shared__ __align__(16) short xt[6*48*32];   // 6-row window [rc][ci], 18 KB

    int tid = threadIdx.x;
    int bg = blockIdx.x / 18;
    int pt = blockIdx.x % 18;
    int p0 = pt * 128;
    int b = bg >> 3, g = bg & 7;
    int r0 = p0 / 48 - 1;                    // 6 staged rows r0..r0+5
    const float* xb = x + ((size_t)(b*CC + g*DD)) * HWSZ;

    #pragma unroll 6
    for (int i = 0; i < 36; ++i) {
        int cell = tid + i * 256;            // 9216 = 32ci * 288rc
        int ci = cell / 288;
        int rc = cell % 288;
        int row = r0 + rc / 48, col = rc % 48;
        float v = (row >= 0 && row < 48) ? xb[(size_t)ci*HWSZ + row*48 + col] : 0.f;
        xt[rc*32 + ci] = f2bf(v);
    }
    __syncthreads();

    int lane = tid & 63, wave = tid >> 6;
    int l15 = lane & 15, lg = lane >> 4;

    bf16x8 aq[9][2], ak[2], av[2];
    const short* wqg = g_wq + g*9*2*16*32;
    #pragma unroll
    for (int tap = 0; tap < 9; ++tap)
        #pragma unroll
        for (int mh = 0; mh < 2; ++mh)
            aq[tap][mh] = *(const bf16x8*)&wqg[((tap*2 + mh)*16 + l15)*32 + lg*8];
    #pragma unroll
    for (int mh = 0; mh < 2; ++mh) {
        ak[mh] = *(const bf16x8*)&g_wk[(g*32 + mh*16 + l15)*32 + lg*8];
        av[mh] = *(const bf16x8*)&g_wv[(g*32 + mh*16 + l15)*32 + lg*8];
    }
    float bqv[2][4], bkv[2][4], bvv[2][4];
    #pragma unroll
    for (int mh = 0; mh < 2; ++mh)
        #pragma unroll
        for (int j = 0; j < 4; ++j) {
            int c = g*32 + mh*16 + lg*4 + j;
            bqv[mh][j] = bq[c]; bkv[mh][j] = bk[c]; bvv[mh][j] = bv[c];
        }

    int p0w = p0 + wave * 32;
    size_t qkb = (size_t)bg * HWSZ * DD;
    size_t vb  = (size_t)bg * DD * HWSZ;
    const f32x4 zero = {0.f,0.f,0.f,0.f};

    #pragma unroll
    for (int nf = 0; nf < 2; ++nf) {
        int n = p0w + nf*16 + l15;
        int y = n / 48, xcol = n % 48;
        int cell = (y - r0) * 48 + xcol;
        f32x4 cq0 = zero, cq1 = zero, ck0 = zero, ck1 = zero, cv0 = zero, cv1 = zero;
        #pragma unroll
        for (int tap = 0; tap < 9; ++tap) {
            int dy = tap / 3 - 1, dx = tap % 3 - 1;
            int xc = xcol + dx;
            bool ok = (unsigned)xc < 48u;
            int idx = ok ? (cell + dy*48 + dx)*32 + lg*8 : lg*8;
            bf16x8 bx = *(const bf16x8*)&xt[idx];
            if (!ok) bx = bf16x8{0,0,0,0,0,0,0,0};
            cq0 = __builtin_amdgcn_mfma_f32_16x16x32_bf16(aq[tap][0], bx, cq0, 0, 0, 0);
            cq1 = __builtin_amdgcn_mfma_f32_16x16x32_bf16(aq[tap][1], bx, cq1, 0, 0, 0);
            if (tap == 4) {
                ck0 = __builtin_amdgcn_mfma_f32_16x16x32_bf16(ak[0], bx, ck0, 0, 0, 0);
                ck1 = __builtin_amdgcn_mfma_f32_16x16x32_bf16(ak[1], bx, ck1, 0, 0, 0);
                cv0 = __builtin_amdgcn_mfma_f32_16x16x32_bf16(av[0], bx, cv0, 0, 0, 0);
                cv1 = __builtin_amdgcn_mfma_f32_16x16x32_bf16(av[1], bx, cv1, 0, 0, 0);
            }
        }
        int tile = n >> 6, key = n & 63;
        #pragma unroll
        for (int mh = 0; mh < 2; ++mh) {
            f32x4 aQ = mh ? cq1 : cq0;
            f32x4 aK = mh ? ck1 : ck0;
            f32x4 aV = mh ? cv1 : cv0;
            s16x4 pq, pk;
            #pragma unroll
            for (int j = 0; j < 4; ++j) {
                pq[j] = f2bf((aQ[j] + bqv[mh][j]) * ATTN_SCALE);
                pk[j] = f2bf(aK[j] + bkv[mh][j]);
            }
            *(s16x4*)&g_q[qkb + (size_t)n*32 + mh*16 + lg*4] = pq;
            *(s16x4*)&g_k[qkb + (size_t)n*32 + mh*16 + lg*4] = pk;
            #pragma unroll
            for (int j = 0; j < 4; ++j)
                g_v[vb + (size_t)tile*VTILE + (mh*16 + lg*4 + j)*64 + key]
                    = f2bf(aV[j] + bvv[mh][j]);
        }
    }
}

// ---------------- attention: 48q/wave, key-split, in-block combine ----------------
// block = 256 thr = 4 waves (= 4 ks segments); one barrier; writes final
// normalized fp32 O. Grid 768 = exactly 3 blocks/CU.
__global__ __launch_bounds__(256) void attn_mfma()
{
    __shared__ float cmb[KSPLIT][48][34];   // [ks][q][d], pad 34 -> 26.1 KB
    __shared__ float cmbl[KSPLIT][48];

    int tid  = threadIdx.x;
    int lane = tid & 63;
    int ks   = tid >> 6;             // wave = key-split segment
    int l15 = lane & 15;
    int lg  = lane >> 4;
    int bg = blockIdx.x & 15;        // XCD clustering: bg, bg+8 per XCD
    int qt = blockIdx.x >> 4;        // 0..47 (48-query tiles)

    const short* qg = g_q + (size_t)bg * HWSZ * DD;
    const short* kg = g_k + (size_t)bg * HWSZ * DD;
    const short* vg = g_v + (size_t)bg * DD * HWSZ;
    int k0 = ks * KSEG;

    bf16x8 aq0 = *(const bf16x8*)&qg[(size_t)(qt*48 + l15)*32 + lg*8];
    bf16x8 aq1 = *(const bf16x8*)&qg[(size_t)(qt*48 + 16 + l15)*32 + lg*8];
    bf16x8 aq2 = *(const bf16x8*)&qg[(size_t)(qt*48 + 32 + l15)*32 + lg*8];

    f32x4 oc00 = {0.f,0.f,0.f,0.f}, oc01 = {0.f,0.f,0.f,0.f};
    f32x4 oc10 = {0.f,0.f,0.f,0.f}, oc11 = {0.f,0.f,0.f,0.f};
    f32x4 oc20 = {0.f,0.f,0.f,0.f}, oc21 = {0.f,0.f,0.f,0.f};
    const f32x4 zero = {0.f,0.f,0.f,0.f};
    float lsum0 = 0.f, lsum1 = 0.f, lsum2 = 0.f;

    bf16x8 ck[4], cv[4];
    #pragma unroll
    for (int kb = 0; kb < 4; ++kb)
        ck[kb] = *(const bf16x8*)&kg[(size_t)(k0 + kb*16 + l15)*32 + lg*8];
    {
        const short* vt = vg + (size_t)(ks*9) * VTILE;
        #pragma unroll
        for (int h = 0; h < 2; ++h)
            #pragma unroll
            for (int w = 0; w < 2; ++w)
                cv[h*2+w] = *(const bf16x8*)&vt[(w*16 + l15)*64 + h*32 + lg*8];
    }

    for (int t = 0; t < KSEG/64; ++t) {
        int tn = (t + 1 < KSEG/64) ? t + 1 : 0;
        int mm = k0 + tn * 64;
        const short* vtn = vg + (size_t)(ks*9 + tn) * VTILE;
        bf16x8 nk[4], nv[4];
        #pragma unroll
        for (int kb = 0; kb < 4; ++kb)
            nk[kb] = *(const bf16x8*)&kg[(size_t)(mm + kb*16 + l15)*32 + lg*8];
        #pragma unroll
        for (int h = 0; h < 2; ++h)
            #pragma unroll
            for (int w = 0; w < 2; ++w)
                nv[h*2+w] = *(const bf16x8*)&vtn[(w*16 + l15)*64 + h*32 + lg*8];

        #pragma unroll
        for (int qf = 0; qf < 3; ++qf) {
            bf16x8 aq = qf == 0 ? aq0 : (qf == 1 ? aq1 : aq2);
            f32x4 s[4];
            #pragma unroll
            for (int kb = 0; kb < 4; ++kb)
                s[kb] = __builtin_amdgcn_mfma_f32_16x16x32_bf16(ck[kb], aq, zero, 0, 0, 0);
            unsigned W[4][2];
            float ls = 0.f;
            #pragma unroll
            for (int kb = 0; kb < 4; ++kb) {
                float p0 = EXP2F(s[kb][0]), p1 = EXP2F(s[kb][1]);
                float p2 = EXP2F(s[kb][2]), p3 = EXP2F(s[kb][3]);
                ls += (p0 + p1) + (p2 + p3);
                W[kb][0] = cvt_pk_bf16(p0, p1);
                W[kb][1] = cvt_pk_bf16(p2, p3);
            }
            if (qf == 0) lsum0 += ls; else if (qf == 1) lsum1 += ls; else lsum2 += ls;
            #pragma unroll
            for (int h = 0; h < 2; ++h) {
                unsigned a0 = W[2*h][0], b0 = W[2*h+1][0];
                asm("v_permlane32_swap_b32 %0, %1" : "+v"(a0), "+v"(b0));
                asm("v_permlane16_swap_b32 %0, %1" : "+v"(a0), "+v"(b0));
                unsigned a1 = W[2*h][1], b1 = W[2*h+1][1];
                asm("v_permlane32_swap_b32 %0, %1" : "+v"(a1), "+v"(b1));
                asm("v_permlane16_swap_b32 %0, %1" : "+v"(a1), "+v"(b1));
                union { unsigned u[4]; bf16x8 v; } fr;
                fr.u[0] = a0; fr.u[1] = a1; fr.u[2] = b0; fr.u[3] = b1;
                if (qf == 0) {
                    oc00 = __builtin_amdgcn_mfma_f32_16x16x32_bf16(cv[h*2+0], fr.v, oc00, 0, 0, 0);
                    oc01 = __builtin_amdgcn_mfma_f32_16x16x32_bf16(cv[h*2+1], fr.v, oc01, 0, 0, 0);
                } else if (qf == 1) {
                    oc10 = __builtin_amdgcn_mfma_f32_16x16x32_bf16(cv[h*2+0], fr.v, oc10, 0, 0, 0);
                    oc11 = __builtin_amdgcn_mfma_f32_16x16x32_bf16(cv[h*2+1], fr.v, oc11, 0, 0, 0);
                } else {
                    oc20 = __builtin_amdgcn_mfma_f32_16x16x32_bf16(cv[h*2+0], fr.v, oc20, 0, 0, 0);
                    oc21 = __builtin_amdgcn_mfma_f32_16x16x32_bf16(cv[h*2+1], fr.v, oc21, 0, 0, 0);
                }
            }
        }

        #pragma unroll
        for (int kb = 0; kb < 4; ++kb) ck[kb] = nk[kb];
        #pragma unroll
        for (int i = 0; i < 4; ++i) cv[i] = nv[i];
    }

    // per-wave denominators (across lg groups; q = l15 column)
    lsum0 += __shfl_xor(lsum0, 16, 64);
    lsum0 += __shfl_xor(lsum0, 32, 64);
    lsum1 += __shfl_xor(lsum1, 16, 64);
    lsum1 += __shfl_xor(lsum1, 32, 64);
    lsum2 += __shfl_xor(lsum2, 16, 64);
    lsum2 += __shfl_xor(lsum2, 32, 64);

    // deposit this wave's partials in LDS
    #pragma unroll
    for (int qf = 0; qf < 3; ++qf) {
        f32x4 a = qf == 0 ? oc00 : (qf == 1 ? oc10 : oc20);
        f32x4 b = qf == 0 ? oc01 : (qf == 1 ? oc11 : oc21);
        #pragma unroll
        for (int j = 0; j < 4; ++j) {
            cmb[ks][qf*16 + l15][lg*4 + j]      = a[j];
            cmb[ks][qf*16 + l15][16 + lg*4 + j] = b[j];
        }
    }
    if (lg == 0) {
        cmbl[ks][l15]      = lsum0;
        cmbl[ks][16 + l15] = lsum1;
        cmbl[ks][32 + l15] = lsum2;
    }
    __syncthreads();

    // combine + normalize + store final O (coalesced along n)
    size_t ob = (size_t)bg * DD * HWSZ;
    int n0 = qt * 48;
    for (int i = tid; i < 48*DD; i += 256) {
        int q = i % 48, d = i / 48;
        float num = cmb[0][q][d] + cmb[1][q][d] + cmb[2][q][d] + cmb[3][q][d];
        float den = cmbl[0][q] + cmbl[1][q] + cmbl[2][q] + cmbl[3][q];
        g_o[ob + (size_t)d * HWSZ + n0 + q] = num / den;
    }
}

// ---------------- BN (training-mode batch stats) + affine + ReLU ----------------
__global__ __launch_bounds__(256) void bn_relu(
    const float* __restrict__ gamma, const float* __restrict__ beta,
    float* __restrict__ out)
{
    __shared__ float rs[4], rss[4];
    __shared__ float smean, sinv;
    int c = blockIdx.x;
    int tid = threadIdx.x;
    const float* o0 = g_o + (size_t)c * HWSZ;          // channel-major matches [bg][d][n]
    const float* o1 = g_o + (size_t)(CC + c) * HWSZ;

    float s = 0.f, ss = 0.f;
    for (int i = tid; i < HWSZ; i += 256) {
        float v0 = o0[i], v1 = o1[i];
        s += v0 + v1;
        ss += v0 * v0 + v1 * v1;
    }
    #pragma unroll
    for (int off = 32; off; off >>= 1) {
        s  += __shfl_down(s, off, 64);
        ss += __shfl_down(ss, off, 64);
    }
    int wid = tid >> 6, lane = tid & 63;
    if (lane == 0) { rs[wid] = s; rss[wid] = ss; }
    __syncthreads();
    if (tid == 0) {
        float ts  = rs[0] + rs[1] + rs[2] + rs[3];
        float tss = rss[0] + rss[1] + rss[2] + rss[3];
        float mean = ts / (float)NHW;
        float var  = tss / (float)NHW - mean * mean;
        smean = mean;
        sinv  = rsqrtf(var + 1e-5f);
    }
    __syncthreads();
    float mean = smean, inv = sinv;
    float ga = gamma[c], be = beta[c];
    float* out0 = out + (size_t)c * HWSZ;
    float* out1 = out + (size_t)(CC + c) * HWSZ;
    for (int i = tid; i < HWSZ; i += 256) {
        float v0 = (o0[i] - mean) * inv * ga + be;
        float v1 = (o1[i] - mean) * inv * ga + be;
        out0[i] = fmaxf(v0, 0.f);
        out1[i] = fmaxf(v1, 0.f);
    }
}

extern "C" void kernel_launch(void* const* d_in, const int* in_sizes, int n_in,
                              void* d_out, int out_size, void* d_ws, size_t ws_size,
                              hipStream_t stream)
{
    const float* x     = (const float*)d_in[0];
    const float* Wq    = (const float*)d_in[1];
    const float* bq    = (const float*)d_in[2];
    const float* Wk    = (const float*)d_in[3];
    const float* bk    = (const float*)d_in[4];
    const float* Wv    = (const float*)d_in[5];
    const float* bv    = (const float*)d_in[6];
    const float* gamma = (const float*)d_in[7];
    const float* beta  = (const float*)d_in[8];
    float* out = (float*)d_out;

    pack_w<<<(CC*DD*9 + 2*CC*DD + 255) / 256, 256, 0, stream>>>(Wq, Wk, Wv);
    conv_mfma<<<NBG * 18, 256, 0, stream>>>(x, bq, bk, bv);
    attn_mfma<<<NBG * 48, 256, 0, stream>>>();
    bn_relu<<<CC, 256, 0, stream>>>(gamma, beta, out);
}

// Round 16
// 58.022 us; speedup vs baseline: 2.0140x; 1.0029x over previous
//
#include <hip/hip_runtime.h>
#include <math.h>

#define BB 2
#define CC 256
#define GG 8
#define DD 32
#define HH 48
#define WW 48
#define HWSZ (HH*WW)        /* 2304 */
#define NHW (BB*HWSZ)       /* 4608 */
#define TOT (BB*CC*HWSZ)    /* 1179648 */
#define NBG (BB*GG)         /* 16 */
#define KSPLIT 4
#define KSEG (HWSZ/KSPLIT)  /* 576 keys per split = 9 tiles */
#define VTILE 2048          /* shorts per V^T tile: 32 d x 64 keys */
/* 1/sqrt(32) * log2(e): Q pre-scale so softmax runs in exp2 domain */
#define ATTN_SCALE (0.17677669529663687f * 1.4426950408889634f)

__device__ __align__(16) short g_q[NBG*HWSZ*DD];          // [bg][n][d] bf16, pre-scaled
__device__ __align__(16) short g_k[NBG*HWSZ*DD + 2048];   // [bg][n][d] bf16 (+pad: tail prefetch)
__device__ __align__(16) short g_v[NBG*DD*HWSZ + 2048];   // [bg][tile][d][64key] bf16 (+pad)
__device__ __align__(16) float g_o[TOT];                  // [bg][d][n] fp32 (= channel-major)
__device__ __align__(16) short g_wq[GG*9*2*16*32];        // [g][tap][mh][l15][ci] bf16
__device__ __align__(16) short g_wk[CC*DD];               // [c][ci] bf16
__device__ __align__(16) short g_wv[CC*DD];               // [c][ci] bf16

typedef __attribute__((ext_vector_type(8))) short bf16x8;
typedef __attribute__((ext_vector_type(4))) short s16x4;
typedef __attribute__((ext_vector_type(4))) float f32x4;

__device__ __forceinline__ short f2bf(float f) {
    union { float f; unsigned u; } uf; uf.f = f;
    unsigned r = uf.u + 0x7fff + ((uf.u >> 16) & 1);  // RNE
    return (short)(r >> 16);
}
__device__ __forceinline__ unsigned cvt_pk_bf16(float lo, float hi) {
    unsigned w;
    asm("v_cvt_pk_bf16_f32 %0, %1, %2" : "=v"(w) : "v"(lo), "v"(hi));
    return w;
}
#if __has_builtin(__builtin_amdgcn_exp2f)
#define EXP2F(x) __builtin_amdgcn_exp2f(x)
#else
#define EXP2F(x) exp2f(x)
#endif

// ---------------- weight pre-pack ----------------
__global__ __launch_bounds__(256) void pack_w(
    const float* __restrict__ Wq, const float* __restrict__ Wk,
    const float* __restrict__ Wv)
{
    int t = blockIdx.x * 256 + threadIdx.x;
    if (t < CC*DD*9) {                       // 73728
        int c = t / 288, r = t % 288, ci = r / 9, tap = r % 9;
        int g = c >> 5, mh = (c >> 4) & 1, l = c & 15;
        g_wq[(((g*9 + tap)*2 + mh)*16 + l)*32 + ci] = f2bf(Wq[t]);
    } else if (t < CC*DD*9 + CC*DD) {
        int i = t - CC*DD*9;
        g_wk[i] = f2bf(Wk[i]);
    } else if (t < CC*DD*9 + 2*CC*DD) {
        int i = t - CC*DD*9 - CC*DD;
        g_wv[i] = f2bf(Wv[i]);
    }
}

// ---------------- conv via implicit-GEMM MFMA: 288 blocks x 128 positions ----------------
// xt pad 40 shorts/row: 80B stride -> staging ds_write spreads across banks
// (pad-32 = 64B stride was a 32-way write conflict).
__global__ __launch_bounds__(256) void conv_mfma(
    const float* __restrict__ x,
    const float* __restrict__ bq, const float* __restrict__ bk,
    const float* __restrict__ bv)
{
    __shared__ __align__(16) short xt[6*48*40];   // [rc][ci] pad 40, 23 KB

    int tid = threadIdx.x;
    int bg = blockIdx.x / 18;
    int pt = blockIdx.x % 18;
    int p0 = pt * 128;
    int b = bg >> 3, g = bg & 7;
    int r0 = p0 / 48 - 1;                    // 6 staged rows r0..r0+5
    const float* xb = x + ((size_t)(b*CC + g*DD)) * HWSZ;

    #pragma unroll 6
    for (int i = 0; i < 36; ++i) {
        int cell = tid + i * 256;            // 9216 = 32ci * 288rc
        int ci = cell / 288;
        int rc = cell % 288;
        int row = r0 + rc / 48, col = rc % 48;
        float v = (row >= 0 && row < 48) ? xb[(size_t)ci*HWSZ + row*48 + col] : 0.f;
        xt[rc*40 + ci] = f2bf(v);
    }
    __syncthreads();

    int lane = tid & 63, wave = tid >> 6;
    int l15 = lane & 15, lg = lane >> 4;

    bf16x8 aq[9][2], ak[2], av[2];
    const short* wqg = g_wq + g*9*2*16*32;
    #pragma unroll
    for (int tap = 0; tap < 9; ++tap)
        #pragma unroll
        for (int mh = 0; mh < 2; ++mh)
            aq[tap][mh] = *(const bf16x8*)&wqg[((tap*2 + mh)*16 + l15)*32 + lg*8];
    #pragma unroll
    for (int mh = 0; mh < 2; ++mh) {
        ak[mh] = *(const bf16x8*)&g_wk[(g*32 + mh*16 + l15)*32 + lg*8];
        av[mh] = *(const bf16x8*)&g_wv[(g*32 + mh*16 + l15)*32 + lg*8];
    }
    float bqv[2][4], bkv[2][4], bvv[2][4];
    #pragma unroll
    for (int mh = 0; mh < 2; ++mh)
        #pragma unroll
        for (int j = 0; j < 4; ++j) {
            int c = g*32 + mh*16 + lg*4 + j;
            bqv[mh][j] = bq[c]; bkv[mh][j] = bk[c]; bvv[mh][j] = bv[c];
        }

    int p0w = p0 + wave * 32;
    size_t qkb = (size_t)bg * HWSZ * DD;
    size_t vb  = (size_t)bg * DD * HWSZ;
    const f32x4 zero = {0.f,0.f,0.f,0.f};

    #pragma unroll
    for (int nf = 0; nf < 2; ++nf) {
        int n = p0w + nf*16 + l15;
        int y = n / 48, xcol = n % 48;
        int cell = (y - r0) * 48 + xcol;
        f32x4 cq0 = zero, cq1 = zero, ck0 = zero, ck1 = zero, cv0 = zero, cv1 = zero;
        #pragma unroll
        for (int tap = 0; tap < 9; ++tap) {
            int dy = tap / 3 - 1, dx = tap % 3 - 1;
            int xc = xcol + dx;
            bool ok = (unsigned)xc < 48u;
            int idx = ok ? (cell + dy*48 + dx)*40 + lg*8 : lg*8;
            bf16x8 bx = *(const bf16x8*)&xt[idx];
            if (!ok) bx = bf16x8{0,0,0,0,0,0,0,0};
            cq0 = __builtin_amdgcn_mfma_f32_16x16x32_bf16(aq[tap][0], bx, cq0, 0, 0, 0);
            cq1 = __builtin_amdgcn_mfma_f32_16x16x32_bf16(aq[tap][1], bx, cq1, 0, 0, 0);
            if (tap == 4) {
                ck0 = __builtin_amdgcn_mfma_f32_16x16x32_bf16(ak[0], bx, ck0, 0, 0, 0);
                ck1 = __builtin_amdgcn_mfma_f32_16x16x32_bf16(ak[1], bx, ck1, 0, 0, 0);
                cv0 = __builtin_amdgcn_mfma_f32_16x16x32_bf16(av[0], bx, cv0, 0, 0, 0);
                cv1 = __builtin_amdgcn_mfma_f32_16x16x32_bf16(av[1], bx, cv1, 0, 0, 0);
            }
        }
        int tile = n >> 6, key = n & 63;
        #pragma unroll
        for (int mh = 0; mh < 2; ++mh) {
            f32x4 aQ = mh ? cq1 : cq0;
            f32x4 aK = mh ? ck1 : ck0;
            f32x4 aV = mh ? cv1 : cv0;
            s16x4 pq, pk;
            #pragma unroll
            for (int j = 0; j < 4; ++j) {
                pq[j] = f2bf((aQ[j] + bqv[mh][j]) * ATTN_SCALE);
                pk[j] = f2bf(aK[j] + bkv[mh][j]);
            }
            *(s16x4*)&g_q[qkb + (size_t)n*32 + mh*16 + lg*4] = pq;
            *(s16x4*)&g_k[qkb + (size_t)n*32 + mh*16 + lg*4] = pk;
            #pragma unroll
            for (int j = 0; j < 4; ++j)
                g_v[vb + (size_t)tile*VTILE + (mh*16 + lg*4 + j)*64 + key]
                    = f2bf(aV[j] + bvv[mh][j]);
        }
    }
}

// ---------------- attention: 48q/wave, key-split, pointer-marching loads ----------------
// block = 256 thr = 4 waves (= 4 ks segments); one barrier; writes final
// normalized fp32 O. Grid 768 = exactly 3 blocks/CU. Per-iter addressing:
// two pointer increments; per-lane offsets + compile-time imms do the rest.
__global__ __launch_bounds__(256) void attn_mfma()
{
    __shared__ float cmb[KSPLIT][48][34];   // [ks][q][d], pad 34 -> 26.1 KB
    __shared__ float cmbl[KSPLIT][48];

    int tid  = threadIdx.x;
    int lane = tid & 63;
    int ks   = tid >> 6;             // wave = key-split segment
    int l15 = lane & 15;
    int lg  = lane >> 4;
    int bg = blockIdx.x & 15;        // XCD clustering: bg, bg+8 per XCD
    int qt = blockIdx.x >> 4;        // 0..47 (48-query tiles)

    const short* qg = g_q + (size_t)bg * HWSZ * DD;
    const short* kg = g_k + (size_t)bg * HWSZ * DD;
    const short* vg = g_v + (size_t)bg * DD * HWSZ;
    int k0 = ks * KSEG;

    bf16x8 aq0 = *(const bf16x8*)&qg[(size_t)(qt*48 + l15)*32 + lg*8];
    bf16x8 aq1 = *(const bf16x8*)&qg[(size_t)(qt*48 + 16 + l15)*32 + lg*8];
    bf16x8 aq2 = *(const bf16x8*)&qg[(size_t)(qt*48 + 32 + l15)*32 + lg*8];

    f32x4 oc00 = {0.f,0.f,0.f,0.f}, oc01 = {0.f,0.f,0.f,0.f};
    f32x4 oc10 = {0.f,0.f,0.f,0.f}, oc11 = {0.f,0.f,0.f,0.f};
    f32x4 oc20 = {0.f,0.f,0.f,0.f}, oc21 = {0.f,0.f,0.f,0.f};
    const f32x4 zero = {0.f,0.f,0.f,0.f};
    float lsum0 = 0.f, lsum1 = 0.f, lsum2 = 0.f;

    int koff = l15*32 + lg*8;        // + kb*512 (compile-time) = K frag offset
    int voff = l15*64 + lg*8;        // + w*1024 + h*32 (compile-time) = V frag offset

    const short* kp = kg + (size_t)k0 * 32;          // current K tile
    const short* vp = vg + (size_t)(ks*9) * VTILE;   // current V tile

    bf16x8 ck[4], cv[4];
    #pragma unroll
    for (int kb = 0; kb < 4; ++kb)
        ck[kb] = *(const bf16x8*)&kp[koff + kb*512];
    #pragma unroll
    for (int h = 0; h < 2; ++h)
        #pragma unroll
        for (int w = 0; w < 2; ++w)
            cv[h*2+w] = *(const bf16x8*)&vp[voff + w*1024 + h*32];

    const short* kq = kp + 2048;     // prefetch pointers (march by one tile)
    const short* vq = vp + VTILE;

    for (int t = 0; t < KSEG/64; ++t) {
        // unconditional prefetch; final iteration reads the pad region (discarded)
        bf16x8 nk[4], nv[4];
        #pragma unroll
        for (int kb = 0; kb < 4; ++kb)
            nk[kb] = *(const bf16x8*)&kq[koff + kb*512];
        #pragma unroll
        for (int h = 0; h < 2; ++h)
            #pragma unroll
            for (int w = 0; w < 2; ++w)
                nv[h*2+w] = *(const bf16x8*)&vq[voff + w*1024 + h*32];

        #pragma unroll
        for (int qf = 0; qf < 3; ++qf) {
            bf16x8 aq = qf == 0 ? aq0 : (qf == 1 ? aq1 : aq2);
            f32x4 s[4];
            #pragma unroll
            for (int kb = 0; kb < 4; ++kb)
                s[kb] = __builtin_amdgcn_mfma_f32_16x16x32_bf16(ck[kb], aq, zero, 0, 0, 0);
            unsigned W[4][2];
            float ls = 0.f;
            #pragma unroll
            for (int kb = 0; kb < 4; ++kb) {
                float p0 = EXP2F(s[kb][0]), p1 = EXP2F(s[kb][1]);
                float p2 = EXP2F(s[kb][2]), p3 = EXP2F(s[kb][3]);
                ls += (p0 + p1) + (p2 + p3);
                W[kb][0] = cvt_pk_bf16(p0, p1);
                W[kb][1] = cvt_pk_bf16(p2, p3);
            }
            if (qf == 0) lsum0 += ls; else if (qf == 1) lsum1 += ls; else lsum2 += ls;
            #pragma unroll
            for (int h = 0; h < 2; ++h) {
                unsigned a0 = W[2*h][0], b0 = W[2*h+1][0];
                asm("v_permlane32_swap_b32 %0, %1" : "+v"(a0), "+v"(b0));
                asm("v_permlane16_swap_b32 %0, %1" : "+v"(a0), "+v"(b0));
                unsigned a1 = W[2*h][1], b1 = W[2*h+1][1];
                asm("v_permlane32_swap_b32 %0, %1" : "+v"(a1), "+v"(b1));
                asm("v_permlane16_swap_b32 %0, %1" : "+v"(a1), "+v"(b1));
                union { unsigned u[4]; bf16x8 v; } fr;
                fr.u[0] = a0; fr.u[1] = a1; fr.u[2] = b0; fr.u[3] = b1;
                if (qf == 0) {
                    oc00 = __builtin_amdgcn_mfma_f32_16x16x32_bf16(cv[h*2+0], fr.v, oc00, 0, 0, 0);
                    oc01 = __builtin_amdgcn_mfma_f32_16x16x32_bf16(cv[h*2+1], fr.v, oc01, 0, 0, 0);
                } else if (qf == 1) {
                    oc10 = __builtin_amdgcn_mfma_f32_16x16x32_bf16(cv[h*2+0], fr.v, oc10, 0, 0, 0);
                    oc11 = __builtin_amdgcn_mfma_f32_16x16x32_bf16(cv[h*2+1], fr.v, oc11, 0, 0, 0);
                } else {
                    oc20 = __builtin_amdgcn_mfma_f32_16x16x32_bf16(cv[h*2+0], fr.v, oc20, 0, 0, 0);
                    oc21 = __builtin_amdgcn_mfma_f32_16x16x32_bf16(cv[h*2+1], fr.v, oc21, 0, 0, 0);
                }
            }
        }

        #pragma unroll
        for (int kb = 0; kb < 4; ++kb) ck[kb] = nk[kb];
        #pragma unroll
        for (int i = 0; i < 4; ++i) cv[i] = nv[i];
        kq += 2048;
        vq += VTILE;
    }

    // per-wave denominators (across lg groups; q = l15 column)
    lsum0 += __shfl_xor(lsum0, 16, 64);
    lsum0 += __shfl_xor(lsum0, 32, 64);
    lsum1 += __shfl_xor(lsum1, 16, 64);
    lsum1 += __shfl_xor(lsum1, 32, 64);
    lsum2 += __shfl_xor(lsum2, 16, 64);
    lsum2 += __shfl_xor(lsum2, 32, 64);

    // deposit this wave's partials in LDS
    #pragma unroll
    for (int qf = 0; qf < 3; ++qf) {
        f32x4 a = qf == 0 ? oc00 : (qf == 1 ? oc10 : oc20);
        f32x4 b = qf == 0 ? oc01 : (qf == 1 ? oc11 : oc21);
        #pragma unroll
        for (int j = 0; j < 4; ++j) {
            cmb[ks][qf*16 + l15][lg*4 + j]      = a[j];
            cmb[ks][qf*16 + l15][16 + lg*4 + j] = b[j];
        }
    }
    if (lg == 0) {
        cmbl[ks][l15]      = lsum0;
        cmbl[ks][16 + l15] = lsum1;
        cmbl[ks][32 + l15] = lsum2;
    }
    __syncthreads();

    // combine + normalize + store final O (coalesced along n)
    size_t ob = (size_t)bg * DD * HWSZ;
    int n0 = qt * 48;
    for (int i = tid; i < 48*DD; i += 256) {
        int q = i % 48, d = i / 48;
        float num = cmb[0][q][d] + cmb[1][q][d] + cmb[2][q][d] + cmb[3][q][d];
        float den = cmbl[0][q] + cmbl[1][q] + cmbl[2][q] + cmbl[3][q];
        g_o[ob + (size_t)d * HWSZ + n0 + q] = num / den;
    }
}

// ---------------- BN (training-mode batch stats) + affine + ReLU ----------------
__global__ __launch_bounds__(256) void bn_relu(
    const float* __restrict__ gamma, const float* __restrict__ beta,
    float* __restrict__ out)
{
    __shared__ float rs[4], rss[4];
    __shared__ float smean, sinv;
    int c = blockIdx.x;
    int tid = threadIdx.x;
    const float* o0 = g_o + (size_t)c * HWSZ;          // channel-major matches [bg][d][n]
    const float* o1 = g_o + (size_t)(CC + c) * HWSZ;

    float s = 0.f, ss = 0.f;
    for (int i = tid; i < HWSZ; i += 256) {
        float v0 = o0[i], v1 = o1[i];
        s += v0 + v1;
        ss += v0 * v0 + v1 * v1;
    }
    #pragma unroll
    for (int off = 32; off; off >>= 1) {
        s  += __shfl_down(s, off, 64);
        ss += __shfl_down(ss, off, 64);
    }
    int wid = tid >> 6, lane = tid & 63;
    if (lane == 0) { rs[wid] = s; rss[wid] = ss; }
    __syncthreads();
    if (tid == 0) {
        float ts  = rs[0] + rs[1] + rs[2] + rs[3];
        float tss = rss[0] + rss[1] + rss[2] + rss[3];
        float mean = ts / (float)NHW;
        float var  = tss / (float)NHW - mean * mean;
        smean = mean;
        sinv  = rsqrtf(var + 1e-5f);
    }
    __syncthreads();
    float mean = smean, inv = sinv;
    float ga = gamma[c], be = beta[c];
    float* out0 = out + (size_t)c * HWSZ;
    float* out1 = out + (size_t)(CC + c) * HWSZ;
    for (int i = tid; i < HWSZ; i += 256) {
        float v0 = (o0[i] - mean) * inv * ga + be;
        float v1 = (o1[i] - mean) * inv * ga + be;
        out0[i] = fmaxf(v0, 0.f);
        out1[i] = fmaxf(v1, 0.f);
    }
}

extern "C" void kernel_launch(void* const* d_in, const int* in_sizes, int n_in,
                              void* d_out, int out_size, void* d_ws, size_t ws_size,
                              hipStream_t stream)
{
    const float* x     = (const float*)d_in[0];
    const float* Wq    = (const float*)d_in[1];
    const float* bq    = (const float*)d_in[2];
    const float* Wk    = (const float*)d_in[3];
    const float* bk    = (const float*)d_in[4];
    const float* Wv    = (const float*)d_in[5];
    const float* bv    = (const float*)d_in[6];
    const float* gamma = (const float*)d_in[7];
    const float* beta  = (const float*)d_in[8];
    float* out = (float*)d_out;

    pack_w<<<(CC*DD*9 + 2*CC*DD + 255) / 256, 256, 0, stream>>>(Wq, Wk, Wv);
    conv_mfma<<<NBG * 18, 256, 0, stream>>>(x, bq, bk, bv);
    attn_mfma<<<NBG * 48, 256, 0, stream>>>();
    bn_relu<<<CC, 256, 0, stream>>>(gamma, beta, out);
}

// Round 18
// 52.909 us; speedup vs baseline: 2.2086x; 1.0966x over previous
//
#include <hip/hip_runtime.h>
#include <math.h>

#define BB 2
#define CC 256
#define GG 8
#define DD 32
#define HH 48
#define WW 48
#define HWSZ (HH*WW)        /* 2304 */
#define NHW (BB*HWSZ)       /* 4608 */
#define TOT (BB*CC*HWSZ)    /* 1179648 */
#define NBG (BB*GG)         /* 16 */
#define KSPLIT 4
#define KSEG (HWSZ/KSPLIT)  /* 576 keys per split = 9 tiles */
#define VTILE 2048          /* shorts per V^T tile: 32 d x 64 keys */
/* 1/sqrt(32) * log2(e): Q pre-scale so softmax runs in exp2 domain */
#define ATTN_SCALE (0.17677669529663687f * 1.4426950408889634f)

__device__ __align__(16) short g_q[NBG*HWSZ*DD];          // [bg][n][d] bf16, pre-scaled
__device__ __align__(16) short g_k[NBG*HWSZ*DD + 2048];   // [bg][n][d] bf16 (+pad: tail prefetch)
__device__ __align__(16) short g_v[NBG*DD*HWSZ + 2048];   // [bg][tile][d][64key] bf16 (+pad)
__device__ __align__(16) float g_o[TOT];                  // [bg][d][n] fp32 (= channel-major)
__device__ __align__(16) short g_wq[GG*9*2*16*32];        // [g][tap][mh][l15][ci] bf16
__device__ __align__(16) short g_wk[CC*DD];               // [c][ci] bf16
__device__ __align__(16) short g_wv[CC*DD];               // [c][ci] bf16

typedef __attribute__((ext_vector_type(8))) short bf16x8;
typedef __attribute__((ext_vector_type(4))) short s16x4;
typedef __attribute__((ext_vector_type(4))) float f32x4;

__device__ __forceinline__ short f2bf(float f) {
    union { float f; unsigned u; } uf; uf.f = f;
    unsigned r = uf.u + 0x7fff + ((uf.u >> 16) & 1);  // RNE
    return (short)(r >> 16);
}
__device__ __forceinline__ unsigned cvt_pk_bf16(float lo, float hi) {
    unsigned w;
    asm("v_cvt_pk_bf16_f32 %0, %1, %2" : "=v"(w) : "v"(lo), "v"(hi));
    return w;
}
#if __has_builtin(__builtin_amdgcn_exp2f)
#define EXP2F(x) __builtin_amdgcn_exp2f(x)
#else
#define EXP2F(x) exp2f(x)
#endif

// ---------------- weight pre-pack ----------------
__global__ __launch_bounds__(256) void pack_w(
    const float* __restrict__ Wq, const float* __restrict__ Wk,
    const float* __restrict__ Wv)
{
    int t = blockIdx.x * 256 + threadIdx.x;
    if (t < CC*DD*9) {                       // 73728
        int c = t / 288, r = t % 288, ci = r / 9, tap = r % 9;
        int g = c >> 5, mh = (c >> 4) & 1, l = c & 15;
        g_wq[(((g*9 + tap)*2 + mh)*16 + l)*32 + ci] = f2bf(Wq[t]);
    } else if (t < CC*DD*9 + CC*DD) {
        int i = t - CC*DD*9;
        g_wk[i] = f2bf(Wk[i]);
    } else if (t < CC*DD*9 + 2*CC*DD) {
        int i = t - CC*DD*9 - CC*DD;
        g_wv[i] = f2bf(Wv[i]);
    }
}

// ---------------- conv via implicit-GEMM MFMA: 576 blocks x 64 positions ----------------
// 4-row halo window; 4 waves x 1 frag each; bg-major decode for XCD locality.
__global__ __launch_bounds__(256) void conv_mfma(
    const float* __restrict__ x,
    const float* __restrict__ bq, const float* __restrict__ bk,
    const float* __restrict__ bv)
{
    __shared__ __align__(16) short xt[4*48*40];   // [rc][ci] pad 40, 15.4 KB

    int tid = threadIdx.x;
    int bg = blockIdx.x & 15;
    int pt = blockIdx.x >> 4;                // 0..35
    int p0 = pt * 64;
    int b = bg >> 3, g = bg & 7;
    int r0 = p0 / 48 - 1;                    // 4 staged rows r0..r0+3
    const float* xb = x + ((size_t)(b*CC + g*DD)) * HWSZ;

    #pragma unroll 4
    for (int i = 0; i < 24; ++i) {
        int cell = tid + i * 256;            // 6144 = 32ci * 192rc
        int ci = cell / 192;
        int rc = cell % 192;
        int row = r0 + rc / 48, col = rc % 48;
        float v = (row >= 0 && row < 48) ? xb[(size_t)ci*HWSZ + row*48 + col] : 0.f;
        xt[rc*40 + ci] = f2bf(v);
    }
    __syncthreads();

    int lane = tid & 63, wave = tid >> 6;
    int l15 = lane & 15, lg = lane >> 4;

    bf16x8 aq[9][2], ak[2], av[2];
    const short* wqg = g_wq + g*9*2*16*32;
    #pragma unroll
    for (int tap = 0; tap < 9; ++tap)
        #pragma unroll
        for (int mh = 0; mh < 2; ++mh)
            aq[tap][mh] = *(const bf16x8*)&wqg[((tap*2 + mh)*16 + l15)*32 + lg*8];
    #pragma unroll
    for (int mh = 0; mh < 2; ++mh) {
        ak[mh] = *(const bf16x8*)&g_wk[(g*32 + mh*16 + l15)*32 + lg*8];
        av[mh] = *(const bf16x8*)&g_wv[(g*32 + mh*16 + l15)*32 + lg*8];
    }
    float bqv[2][4], bkv[2][4], bvv[2][4];
    #pragma unroll
    for (int mh = 0; mh < 2; ++mh)
        #pragma unroll
        for (int j = 0; j < 4; ++j) {
            int c = g*32 + mh*16 + lg*4 + j;
            bqv[mh][j] = bq[c]; bkv[mh][j] = bk[c]; bvv[mh][j] = bv[c];
        }

    size_t qkb = (size_t)bg * HWSZ * DD;
    size_t vb  = (size_t)bg * DD * HWSZ;
    const f32x4 zero = {0.f,0.f,0.f,0.f};

    int n = p0 + wave * 16 + l15;
    int y = n / 48, xcol = n % 48;
    int cell = (y - r0) * 48 + xcol;
    f32x4 cq0 = zero, cq1 = zero, ck0 = zero, ck1 = zero, cv0 = zero, cv1 = zero;
    #pragma unroll
    for (int tap = 0; tap < 9; ++tap) {
        int dy = tap / 3 - 1, dx = tap % 3 - 1;
        int xc = xcol + dx;
        bool ok = (unsigned)xc < 48u;
        int idx = ok ? (cell + dy*48 + dx)*40 + lg*8 : lg*8;
        bf16x8 bx = *(const bf16x8*)&xt[idx];
        if (!ok) bx = bf16x8{0,0,0,0,0,0,0,0};
        cq0 = __builtin_amdgcn_mfma_f32_16x16x32_bf16(aq[tap][0], bx, cq0, 0, 0, 0);
        cq1 = __builtin_amdgcn_mfma_f32_16x16x32_bf16(aq[tap][1], bx, cq1, 0, 0, 0);
        if (tap == 4) {
            ck0 = __builtin_amdgcn_mfma_f32_16x16x32_bf16(ak[0], bx, ck0, 0, 0, 0);
            ck1 = __builtin_amdgcn_mfma_f32_16x16x32_bf16(ak[1], bx, ck1, 0, 0, 0);
            cv0 = __builtin_amdgcn_mfma_f32_16x16x32_bf16(av[0], bx, cv0, 0, 0, 0);
            cv1 = __builtin_amdgcn_mfma_f32_16x16x32_bf16(av[1], bx, cv1, 0, 0, 0);
        }
    }
    int tile = n >> 6, key = n & 63;
    #pragma unroll
    for (int mh = 0; mh < 2; ++mh) {
        f32x4 aQ = mh ? cq1 : cq0;
        f32x4 aK = mh ? ck1 : ck0;
        f32x4 aV = mh ? cv1 : cv0;
        s16x4 pq, pk;
        #pragma unroll
        for (int j = 0; j < 4; ++j) {
            pq[j] = f2bf((aQ[j] + bqv[mh][j]) * ATTN_SCALE);
            pk[j] = f2bf(aK[j] + bkv[mh][j]);
        }
        *(s16x4*)&g_q[qkb + (size_t)n*32 + mh*16 + lg*4] = pq;
        *(s16x4*)&g_k[qkb + (size_t)n*32 + mh*16 + lg*4] = pk;
        #pragma unroll
        for (int j = 0; j < 4; ++j)
            g_v[vb + (size_t)tile*VTILE + (mh*16 + lg*4 + j)*64 + key]
                = f2bf(aV[j] + bvv[mh][j]);
    }
}

// ---------------- attention: 48q/wave, key-split, pointer-marching loads ----------------
// block = 256 thr = 4 waves (= 4 ks segments); one barrier; writes final
// normalized fp32 O. Grid 768 = exactly 3 blocks/CU. (R16-proven structure.)
__global__ __launch_bounds__(256) void attn_mfma()
{
    __shared__ float cmb[KSPLIT][48][34];   // [ks][q][d], pad 34 -> 26.1 KB
    __shared__ float cmbl[KSPLIT][48];

    int tid  = threadIdx.x;
    int lane = tid & 63;
    int ks   = tid >> 6;             // wave = key-split segment
    int l15 = lane & 15;
    int lg  = lane >> 4;
    int bg = blockIdx.x & 15;        // XCD clustering: bg, bg+8 per XCD
    int qt = blockIdx.x >> 4;        // 0..47 (48-query tiles)

    const short* qg = g_q + (size_t)bg * HWSZ * DD;
    const short* kg = g_k + (size_t)bg * HWSZ * DD;
    const short* vg = g_v + (size_t)bg * DD * HWSZ;
    int k0 = ks * KSEG;

    bf16x8 aq0 = *(const bf16x8*)&qg[(size_t)(qt*48 + l15)*32 + lg*8];
    bf16x8 aq1 = *(const bf16x8*)&qg[(size_t)(qt*48 + 16 + l15)*32 + lg*8];
    bf16x8 aq2 = *(const bf16x8*)&qg[(size_t)(qt*48 + 32 + l15)*32 + lg*8];

    f32x4 oc00 = {0.f,0.f,0.f,0.f}, oc01 = {0.f,0.f,0.f,0.f};
    f32x4 oc10 = {0.f,0.f,0.f,0.f}, oc11 = {0.f,0.f,0.f,0.f};
    f32x4 oc20 = {0.f,0.f,0.f,0.f}, oc21 = {0.f,0.f,0.f,0.f};
    const f32x4 zero = {0.f,0.f,0.f,0.f};
    float lsum0 = 0.f, lsum1 = 0.f, lsum2 = 0.f;

    int koff = l15*32 + lg*8;        // + kb*512 (imm) = K frag offset
    int voff = l15*64 + lg*8;        // + w*1024 + h*32 (imm) = V frag offset

    const short* kp = kg + (size_t)k0 * 32;          // current K tile
    const short* vp = vg + (size_t)(ks*9) * VTILE;   // current V tile

    bf16x8 ck[4], cv[4];
    #pragma unroll
    for (int kb = 0; kb < 4; ++kb)
        ck[kb] = *(const bf16x8*)&kp[koff + kb*512];
    #pragma unroll
    for (int h = 0; h < 2; ++h)
        #pragma unroll
        for (int w = 0; w < 2; ++w)
            cv[h*2+w] = *(const bf16x8*)&vp[voff + w*1024 + h*32];

    const short* kq = kp + 2048;     // prefetch pointers (march by one tile)
    const short* vq = vp + VTILE;

    for (int t = 0; t < KSEG/64; ++t) {
        // unconditional prefetch; final iteration reads the pad region (discarded)
        bf16x8 nk[4], nv[4];
        #pragma unroll
        for (int kb = 0; kb < 4; ++kb)
            nk[kb] = *(const bf16x8*)&kq[koff + kb*512];
        #pragma unroll
        for (int h = 0; h < 2; ++h)
            #pragma unroll
            for (int w = 0; w < 2; ++w)
                nv[h*2+w] = *(const bf16x8*)&vq[voff + w*1024 + h*32];

        #pragma unroll
        for (int qf = 0; qf < 3; ++qf) {
            bf16x8 aq = qf == 0 ? aq0 : (qf == 1 ? aq1 : aq2);
            f32x4 s[4];
            #pragma unroll
            for (int kb = 0; kb < 4; ++kb)
                s[kb] = __builtin_amdgcn_mfma_f32_16x16x32_bf16(ck[kb], aq, zero, 0, 0, 0);
            unsigned W[4][2];
            float ls = 0.f;
            #pragma unroll
            for (int kb = 0; kb < 4; ++kb) {
                float p0 = EXP2F(s[kb][0]), p1 = EXP2F(s[kb][1]);
                float p2 = EXP2F(s[kb][2]), p3 = EXP2F(s[kb][3]);
                ls += (p0 + p1) + (p2 + p3);
                W[kb][0] = cvt_pk_bf16(p0, p1);
                W[kb][1] = cvt_pk_bf16(p2, p3);
            }
            if (qf == 0) lsum0 += ls; else if (qf == 1) lsum1 += ls; else lsum2 += ls;
            #pragma unroll
            for (int h = 0; h < 2; ++h) {
                unsigned a0 = W[2*h][0], b0 = W[2*h+1][0];
                asm("v_permlane32_swap_b32 %0, %1" : "+v"(a0), "+v"(b0));
                asm("v_permlane16_swap_b32 %0, %1" : "+v"(a0), "+v"(b0));
                unsigned a1 = W[2*h][1], b1 = W[2*h+1][1];
                asm("v_permlane32_swap_b32 %0, %1" : "+v"(a1), "+v"(b1));
                asm("v_permlane16_swap_b32 %0, %1" : "+v"(a1), "+v"(b1));
                union { unsigned u[4]; bf16x8 v; } fr;
                fr.u[0] = a0; fr.u[1] = a1; fr.u[2] = b0; fr.u[3] = b1;
                if (qf == 0) {
                    oc00 = __builtin_amdgcn_mfma_f32_16x16x32_bf16(cv[h*2+0], fr.v, oc00, 0, 0, 0);
                    oc01 = __builtin_amdgcn_mfma_f32_16x16x32_bf16(cv[h*2+1], fr.v, oc01, 0, 0, 0);
                } else if (qf == 1) {
                    oc10 = __builtin_amdgcn_mfma_f32_16x16x32_bf16(cv[h*2+0], fr.v, oc10, 0, 0, 0);
                    oc11 = __builtin_amdgcn_mfma_f32_16x16x32_bf16(cv[h*2+1], fr.v, oc11, 0, 0, 0);
                } else {
                    oc20 = __builtin_amdgcn_mfma_f32_16x16x32_bf16(cv[h*2+0], fr.v, oc20, 0, 0, 0);
                    oc21 = __builtin_amdgcn_mfma_f32_16x16x32_bf16(cv[h*2+1], fr.v, oc21, 0, 0, 0);
                }
            }
        }

        #pragma unroll
        for (int kb = 0; kb < 4; ++kb) ck[kb] = nk[kb];
        #pragma unroll
        for (int i = 0; i < 4; ++i) cv[i] = nv[i];
        kq += 2048;
        vq += VTILE;
    }

    // per-wave denominators (across lg groups; q = l15 column)
    lsum0 += __shfl_xor(lsum0, 16, 64);
    lsum0 += __shfl_xor(lsum0, 32, 64);
    lsum1 += __shfl_xor(lsum1, 16, 64);
    lsum1 += __shfl_xor(lsum1, 32, 64);
    lsum2 += __shfl_xor(lsum2, 16, 64);
    lsum2 += __shfl_xor(lsum2, 32, 64);

    // deposit this wave's partials in LDS
    #pragma unroll
    for (int qf = 0; qf < 3; ++qf) {
        f32x4 a = qf == 0 ? oc00 : (qf == 1 ? oc10 : oc20);
        f32x4 b = qf == 0 ? oc01 : (qf == 1 ? oc11 : oc21);
        #pragma unroll
        for (int j = 0; j < 4; ++j) {
            cmb[ks][qf*16 + l15][lg*4 + j]      = a[j];
            cmb[ks][qf*16 + l15][16 + lg*4 + j] = b[j];
        }
    }
    if (lg == 0) {
        cmbl[ks][l15]      = lsum0;
        cmbl[ks][16 + l15] = lsum1;
        cmbl[ks][32 + l15] = lsum2;
    }
    __syncthreads();

    // combine + normalize + store final O (coalesced along n)
    size_t ob = (size_t)bg * DD * HWSZ;
    int n0 = qt * 48;
    for (int i = tid; i < 48*DD; i += 256) {
        int q = i % 48, d = i / 48;
        float num = cmb[0][q][d] + cmb[1][q][d] + cmb[2][q][d] + cmb[3][q][d];
        float den = cmbl[0][q] + cmbl[1][q] + cmbl[2][q] + cmbl[3][q];
        g_o[ob + (size_t)d * HWSZ + n0 + q] = num / den;
    }
}

// ---------------- BN (training-mode batch stats) + affine + ReLU ----------------
__global__ __launch_bounds__(256) void bn_relu(
    const float* __restrict__ gamma, const float* __restrict__ beta,
    float* __restrict__ out)
{
    __shared__ float rs[4], rss[4];
    __shared__ float smean, sinv;
    int c = blockIdx.x;
    int tid = threadIdx.x;
    const float* o0 = g_o + (size_t)c * HWSZ;          // channel-major matches [bg][d][n]
    const float* o1 = g_o + (size_t)(CC + c) * HWSZ;

    float s = 0.f, ss = 0.f;
    for (int i = tid; i < HWSZ; i += 256) {
        float v0 = o0[i], v1 = o1[i];
        s += v0 + v1;
        ss += v0 * v0 + v1 * v1;
    }
    #pragma unroll
    for (int off = 32; off; off >>= 1) {
        s  += __shfl_down(s, off, 64);
        ss += __shfl_down(ss, off, 64);
    }
    int wid = tid >> 6, lane = tid & 63;
    if (lane == 0) { rs[wid] = s; rss[wid] = ss; }
    __syncthreads();
    if (tid == 0) {
        float ts  = rs[0] + rs[1] + rs[2] + rs[3];
        float tss = rss[0] + rss[1] + rss[2] + rss[3];
        float mean = ts / (float)NHW;
        float var  = tss / (float)NHW - mean * mean;
        smean = mean;
        sinv  = rsqrtf(var + 1e-5f);
    }
    __syncthreads();
    float mean = smean, inv = sinv;
    float ga = gamma[c], be = beta[c];
    float* out0 = out + (size_t)c * HWSZ;
    float* out1 = out + (size_t)(CC + c) * HWSZ;
    for (int i = tid; i < HWSZ; i += 256) {
        float v0 = (o0[i] - mean) * inv * ga + be;
        float v1 = (o1[i] - mean) * inv * ga + be;
        out0[i] = fmaxf(v0, 0.f);
        out1[i] = fmaxf(v1, 0.f);
    }
}

extern "C" void kernel_launch(void* const* d_in, const int* in_sizes, int n_in,
                              void* d_out, int out_size, void* d_ws, size_t ws_size,
                              hipStream_t stream)
{
    const float* x     = (const float*)d_in[0];
    const float* Wq    = (const float*)d_in[1];
    const float* bq    = (const float*)d_in[2];
    const float* Wk    = (const float*)d_in[3];
    const float* bk    = (const float*)d_in[4];
    const float* Wv    = (const float*)d_in[5];
    const float* bv    = (const float*)d_in[6];
    const float* gamma = (const float*)d_in[7];
    const float* beta  = (const float*)d_in[8];
    float* out = (float*)d_out;

    pack_w<<<(CC*DD*9 + 2*CC*DD + 255) / 256, 256, 0, stream>>>(Wq, Wk, Wv);
    conv_mfma<<<NBG * 36, 256, 0, stream>>>(x, bq, bk, bv);
    attn_mfma<<<NBG * 48, 256, 0, stream>>>();
    bn_relu<<<CC, 256, 0, stream>>>(gamma, beta, out);
}